// Round 9
// baseline (308.787 us; speedup 1.0000x reference)
//
#include <hip/hip_runtime.h>
#include <math.h>

// ---------------------------------------------------------------------------
// CrossPath: dual cross-attention block, MI355X (gfx950).
//   B=4, N=2304, C=256, H=8, D=32, out = 2 x [B,C,96,96] float32
// Inputs float32 (runtime-sniffed). Internal: bf16 MFMA, fp32 accumulation.
// R16: R15 (no-LDS, no-barrier, XCD-affine attn) + explicit 2-tile-deep
// register prefetch of K/V fragments (named sets A/B). R15's counters
// showed ~2200 cyc/tile = exposed L2 latency (compiler issued loads right
// before use). Now set-A loads are issued two tile-computations (~450 cyc)
// before their vmcnt wait. No other kernel changed.
// ---------------------------------------------------------------------------

typedef __attribute__((ext_vector_type(8))) short short8;   // 8 bf16 = 4 VGPRs
typedef __attribute__((ext_vector_type(4))) float f32x4;
typedef __attribute__((ext_vector_type(16))) float f32x16;
typedef __attribute__((ext_vector_type(2))) unsigned uint32x2;

#define MFMA16(a, b, c) __builtin_amdgcn_mfma_f32_16x16x32_bf16((a), (b), (c), 0, 0, 0)
#define MFMA32(a, b, c) __builtin_amdgcn_mfma_f32_32x32x16_bf16((a), (b), (c), 0, 0, 0)

__device__ __forceinline__ float bf2f(ushort u) {
    union { unsigned u; float f; } x; x.u = ((unsigned)u) << 16; return x.f;
}
__device__ __forceinline__ ushort f2bf(float f) {
    union { float f; unsigned u; } x; x.f = f;
    unsigned u = x.u;
    return (ushort)((u + 0x7fffu + ((u >> 16) & 1u)) >> 16);   // RNE
}
// HW packed RNE conversion: D = {bf16(b)<<16 | bf16(a)}
__device__ __forceinline__ unsigned cvt_pk_bf16(float a, float b) {
    unsigned r;
    asm("v_cvt_pk_bf16_f32 %0, %1, %2" : "=v"(r) : "v"(a), "v"(b));
    return r;
}
// Exchange upper 32 lanes of a with lower 32 lanes of b (gfx950 builtin).
__device__ __forceinline__ void plswap(unsigned &a, unsigned &b) {
    uint32x2 r = __builtin_amdgcn_permlane32_swap(a, b, false, false);
    a = r[0]; b = r[1];
}

// ---------------------------------------------------------------------------
// Dtype sniffer: flag=1 means f32 inputs.
// ---------------------------------------------------------------------------
__global__ void sniff_kernel(const ushort* __restrict__ x, int* __restrict__ flag)
{
    int lane = threadIdx.x;
    ushort u = x[lane * 2];
    int e = (u >> 7) & 0xFF;
    int outlier = (e < 100 || e > 135) ? 1 : 0;
    unsigned long long m = __ballot(outlier);
    if (lane == 0) *flag = (__popcll(m) >= 16) ? 1 : 0;
}

// ---------------------------------------------------------------------------
// Canonicalize all 12 weight/param arrays to bf16 at fixed offsets in ws.
// ---------------------------------------------------------------------------
__global__ __launch_bounds__(256) void convert_params(
    const void* s0, const void* s1, const void* s2, const void* s3,
    const void* s4, const void* s5, const void* s6, const void* s7,
    const void* s8, const void* s9, const void* s10, const void* s11,
    ushort* __restrict__ dst, const int* __restrict__ flag)
{
    int idx = blockIdx.x * 256 + threadIdx.x;
    if (idx >= 525824) return;
    const void* src; int off;
    if      (idx < 65536)  { src = s0;  off = idx; }
    else if (idx < 196608) { src = s1;  off = idx - 65536; }
    else if (idx < 262144) { src = s2;  off = idx - 196608; }
    else if (idx < 393216) { src = s3;  off = idx - 262144; }
    else if (idx < 458752) { src = s4;  off = idx - 393216; }
    else if (idx < 524288) { src = s5;  off = idx - 458752; }
    else if (idx < 524544) { src = s6;  off = idx - 524288; }
    else if (idx < 524800) { src = s7;  off = idx - 524544; }
    else if (idx < 525056) { src = s8;  off = idx - 524800; }
    else if (idx < 525312) { src = s9;  off = idx - 525056; }
    else if (idx < 525568) { src = s10; off = idx - 525312; }
    else                   { src = s11; off = idx - 525568; }
    ushort v = (*flag) ? f2bf(((const float*)src)[off])
                       : ((const ushort*)src)[off];
    dst[idx] = v;
}

// ---------------------------------------------------------------------------
// Pre-convert x1/x2 -> bf16 once (8 elems/thread).
// ---------------------------------------------------------------------------
__global__ __launch_bounds__(256) void convert_x(
    const void* __restrict__ x1, const void* __restrict__ x2,
    ushort* __restrict__ o1, ushort* __restrict__ o2,
    const int* __restrict__ flag)
{
    int idx = blockIdx.x * 256 + threadIdx.x;      // 2304 blocks -> 589824 thr
    int which = idx >= 294912;
    int off = (which ? idx - 294912 : idx) * 8;
    const void* src = which ? x2 : x1;
    ushort* dst = which ? o2 : o1;
    if (*flag) {
        const float* p = (const float*)src + off;
        float4 a = *(const float4*)p;
        float4 c = *(const float4*)(p + 4);
        uint4 u;
        u.x = cvt_pk_bf16(a.x, a.y);
        u.y = cvt_pk_bf16(a.z, a.w);
        u.z = cvt_pk_bf16(c.x, c.y);
        u.w = cvt_pk_bf16(c.z, c.w);
        *(uint4*)(dst + off) = u;
    } else {
        *(uint4*)(dst + off) = *(const uint4*)((const ushort*)src + off);
    }
}

// ---------------------------------------------------------------------------
// GEMM: C[M,N] = A[M,K]*W[N,K]^T, bf16 MFMA 16x16x32, tile 64x64, 4 waves.
// Two stacked problems (rows [0,mhalf) use W/bias/Kh/Vt, rows [mhalf,M) use
// W2/bias2/Kh2/Vt2). mode 0: plain C (+bias/relu). mode 1 (merged QKV,
// N=768): col<256 -> Q row-major SCALED by scale*log2e; col<512 ->
// Kh[b][h][tok][32]; else -> Vt[b][h][d][2304].
// ---------------------------------------------------------------------------
__global__ __launch_bounds__(256) void gemm_bt(
    const void* __restrict__ Ain, const ushort* __restrict__ W,
    ushort* __restrict__ C, const ushort* __restrict__ bias,
    int M, int N, int K, int relu, const int* __restrict__ dflag, int a_ext,
    int mode, ushort* __restrict__ Kh, ushort* __restrict__ Vt,
    const ushort* __restrict__ W2, const ushort* __restrict__ bias2,
    ushort* __restrict__ Kh2, ushort* __restrict__ Vt2, int mhalf)
{
    __shared__ __align__(16) ushort As[64][40];
    __shared__ __align__(16) ushort Ws[64][40];

    const int m0 = blockIdx.x * 64;
    const int n0 = blockIdx.y * 64;
    const int tid = threadIdx.x;
    const int w = tid >> 6;
    const int lane = tid & 63;
    const int lm = lane & 15;
    const int quad = lane >> 4;
    const int a32 = a_ext ? *dflag : 0;

    const int side = (mhalf && m0 >= mhalf) ? 1 : 0;
    const ushort* Wu = side ? W2 : W;
    const ushort* bu = side ? bias2 : bias;
    ushort* Khu = side ? Kh2 : Kh;
    ushort* Vtu = side ? Vt2 : Vt;

    const f32x4 Z4 = {0.f, 0.f, 0.f, 0.f};
    f32x4 acc[4];
    for (int j = 0; j < 4; j++) acc[j] = Z4;

    const ushort* A16 = (const ushort*)Ain;
    const float*  A32 = (const float*)Ain;
    const int row = tid >> 2, off = (tid & 3) * 8;

    for (int k0 = 0; k0 < K; k0 += 32) {
        __syncthreads();
        if (a32) {
            const float* p0 = A32 + (size_t)(m0 + row) * K + k0 + off;
            float4 f0 = *(const float4*)p0;
            float4 f1 = *(const float4*)(p0 + 4);
            uint4 t0;
            t0.x = cvt_pk_bf16(f0.x, f0.y);
            t0.y = cvt_pk_bf16(f0.z, f0.w);
            t0.z = cvt_pk_bf16(f1.x, f1.y);
            t0.w = cvt_pk_bf16(f1.z, f1.w);
            *(uint4*)&As[row][off] = t0;
        } else {
            *(uint4*)&As[row][off] =
                *(const uint4*)(A16 + (size_t)(m0 + row) * K + k0 + off);
        }
        *(uint4*)&Ws[row][off] =
            *(const uint4*)(Wu + (size_t)(n0 + row) * K + k0 + off);
        __syncthreads();

        short8 af = *(const short8*)&As[w * 16 + lm][quad * 8];
        for (int nt = 0; nt < 4; nt++) {
            short8 wf = *(const short8*)&Ws[nt * 16 + lm][quad * 8];
            acc[nt] = MFMA16(af, wf, acc[nt]);
        }
    }

    const int grow = m0 + w * 16 + quad * 4;     // global C row (4 consecutive)
    const int grel = grow - (side ? mhalf : 0);  // row within half (Kh/Vt)
    if (mode == 1) {
        const float QSC = 0.17677669529663687f * 1.4426950408889634f;
        int bb = grel / 2304;
        int tok = grel - bb * 2304;              // 4-aligned; same bb for r=0..3
        for (int nt = 0; nt < 4; nt++) {
            int col = n0 + nt * 16 + lm;
            if (col < 256) {
                for (int r = 0; r < 4; r++)
                    C[(size_t)(grow + r) * 256 + col] = f2bf(acc[nt][r] * QSC);
            } else if (col < 512) {
                int c2 = col - 256, hh = c2 >> 5, d = c2 & 31;
                for (int r = 0; r < 4; r++)
                    Khu[(((size_t)bb * 8 + hh) * 2304 + tok + r) * 32 + d] = f2bf(acc[nt][r]);
            } else {
                int c2 = col - 512, hh = c2 >> 5, d = c2 & 31;
                uint2 o;
                o.x = cvt_pk_bf16(acc[nt][0], acc[nt][1]);
                o.y = cvt_pk_bf16(acc[nt][2], acc[nt][3]);
                *(uint2*)&Vtu[(((size_t)bb * 8 + hh) * 32 + d) * 2304 + tok] = o;
            }
        }
    } else {
        for (int nt = 0; nt < 4; nt++) {
            int col = n0 + nt * 16 + lm;
            float bv = bu ? bf2f(bu[col]) : 0.f;
            for (int r = 0; r < 4; r++) {
                float v = acc[nt][r] + bv;
                if (relu) v = fmaxf(v, 0.f);
                C[(size_t)(grow + r) * N + col] = f2bf(v);
            }
        }
    }
}

// ---------------------------------------------------------------------------
// Flash cross-attention, S^T form on 32x32x16 MFMA, no-max softmax
// (p = exp2(s), Q pre-scaled by scale*log2e in the QKV GEMM).
// NO LDS, NO BARRIERS: K/V fragments load directly from global (streams are
// L2-resident; full 64B-line utilization). Explicit 2-tile-deep register
// prefetch: named fragment sets A/B; set-A loads issued two
// tile-computations before their wait. Block = 2 independent waves x 32 q.
// Grid (stream=64, qb=36) keeps a stream's 36 blocks on one XCD.
// Q:[B,2304,256]; Kh:[b][h][tok][32]; Vt:[b][h][d][2304]; O:[B,2304,256].
// ---------------------------------------------------------------------------
__global__ __launch_bounds__(128) void attn_kernel(
    const ushort* __restrict__ Qa, const ushort* __restrict__ Kha,
    const ushort* __restrict__ Vta, ushort* __restrict__ Oa,
    const ushort* __restrict__ Qb, const ushort* __restrict__ Khb2,
    const ushort* __restrict__ Vtb2, ushort* __restrict__ Ob)
{
    const int sid = blockIdx.x;           // 0..63: side*32 + bh (XCD-affine)
    const int qb = blockIdx.y;            // 0..35: 64-q tile
    const int side = sid >> 5;
    const int bh = sid & 31;
    const ushort* Q  = side ? Qb   : Qa;
    const ushort* Kh = side ? Khb2 : Kha;
    const ushort* Vt = side ? Vtb2 : Vta;
    ushort* O        = side ? Ob   : Oa;

    const int b = bh >> 3, h = bh & 7;
    const int tid = threadIdx.x;
    const int w = tid >> 6, lane = tid & 63;
    const int l31 = lane & 31, hl = lane >> 5;

    // Q B-frags: lane holds q-col = l31, d = 16*dstep + hl*8 + j (persistent)
    const int qrow = qb * 64 + w * 32 + l31;
    const ushort* qp = Q + ((size_t)b * 2304 + qrow) * 256 + h * 32 + hl * 8;
    const short8 qf0 = *(const short8*)qp;          // d = hl*8 + j
    const short8 qf1 = *(const short8*)(qp + 16);   // d = 16 + hl*8 + j

    f32x16 o0, o1;
    #pragma unroll
    for (int i = 0; i < 16; i++) { o0[i] = 0.f; o1[i] = 0.f; }
    const f32x16 Z16 = o0;
    float l = 0.f;

    // Per-lane fragment base pointers (direct-from-global).
    // K-frag of 32-key tile t: lane reads Kh[tok=t*32+l31][d=hl*8+j].
    // V-frag of tile t: lane reads Vt[d=l31][tok=t*32+hl*8+j].
    const ushort* kp0 = Kh + (size_t)bh * 2304 * 32 + (size_t)l31 * 32 + hl * 8;
    const ushort* vp0 = Vt + (size_t)bh * 32 * 2304 + (size_t)l31 * 2304 + hl * 8;

#define LOADT(kf0v, kf1v, vf0v, vf1v, t) { \
    const ushort* _kp = kp0 + (size_t)(t) * 1024; \
    kf0v = *(const short8*)_kp; \
    kf1v = *(const short8*)(_kp + 16); \
    const ushort* _vp = vp0 + (t) * 32; \
    vf0v = *(const short8*)_vp; \
    vf1v = *(const short8*)(_vp + 16); \
}
    // One 32-key tile from registers: S^T MFMA pair -> exp2 -> pack/swap ->
    // PV MFMA pair. No LDS, no barriers.
#define COMP(kf0v, kf1v, vf0v, vf1v, oacc) { \
    f32x16 s = MFMA32(kf0v, qf0, Z16); \
    s = MFMA32(kf1v, qf1, s); \
    float p[16]; \
    _Pragma("unroll") \
    for (int i = 0; i < 16; i++) p[i] = exp2f(s[i]); \
    l += (((p[0] + p[1]) + (p[2] + p[3])) + ((p[4] + p[5]) + (p[6] + p[7]))) \
       + (((p[8] + p[9]) + (p[10] + p[11])) + ((p[12] + p[13]) + (p[14] + p[15]))); \
    unsigned c0 = cvt_pk_bf16(p[0],  p[1]); \
    unsigned c1 = cvt_pk_bf16(p[2],  p[3]); \
    unsigned c2 = cvt_pk_bf16(p[4],  p[5]); \
    unsigned c3 = cvt_pk_bf16(p[6],  p[7]); \
    unsigned c4 = cvt_pk_bf16(p[8],  p[9]); \
    unsigned c5 = cvt_pk_bf16(p[10], p[11]); \
    unsigned c6 = cvt_pk_bf16(p[12], p[13]); \
    unsigned c7 = cvt_pk_bf16(p[14], p[15]); \
    plswap(c0, c2); plswap(c1, c3); plswap(c4, c6); plswap(c5, c7); \
    union { unsigned u[4]; short8 s8; } pA, pB; \
    pA.u[0] = c0; pA.u[1] = c1; pA.u[2] = c2; pA.u[3] = c3; \
    pB.u[0] = c4; pB.u[1] = c5; pB.u[2] = c6; pB.u[3] = c7; \
    oacc = MFMA32(vf0v, pA.s8, oacc); \
    oacc = MFMA32(vf1v, pB.s8, oacc); \
}

    short8 ka0, ka1, va0, va1;    // set A: even tiles
    short8 kb0, kb1, vb0, vb1;    // set B: odd tiles

    LOADT(ka0, ka1, va0, va1, 0);
    LOADT(kb0, kb1, vb0, vb1, 1);

    for (int t = 0; t < 72; t += 2) {
        COMP(ka0, ka1, va0, va1, o0);             // tile t
        { int ta = t + 2 < 72 ? t + 2 : 70; LOADT(ka0, ka1, va0, va1, ta); }
        COMP(kb0, kb1, vb0, vb1, o1);             // tile t+1
        { int tb = t + 3 < 72 ? t + 3 : 71; LOADT(kb0, kb1, vb0, vb1, tb); }
    }
#undef LOADT
#undef COMP

    // Lane halves hold disjoint key subsets for the same q: reduce l.
    l += __shfl_xor(l, 32, 64);
    float rl = 1.f / l;
    // o reg r: d = (r&3) + 8*(r>>2) + 4*hl, q = l31.
    ushort* op = O + ((size_t)b * 2304 + qrow) * 256 + h * 32 + hl * 4;
    #pragma unroll
    for (int g = 0; g < 4; g++) {
        float e0 = (o0[4 * g]     + o1[4 * g])     * rl;
        float e1 = (o0[4 * g + 1] + o1[4 * g + 1]) * rl;
        float e2 = (o0[4 * g + 2] + o1[4 * g + 2]) * rl;
        float e3 = (o0[4 * g + 3] + o1[4 * g + 3]) * rl;
        uint2 o;
        o.x = cvt_pk_bf16(e0, e1);
        o.y = cvt_pk_bf16(e2, e3);
        *(uint2*)(op + 8 * g) = o;
    }
}

// ---------------------------------------------------------------------------
// LayerNorm over C=256 fused with transpose to channel-major:
//   Z[18432][256] -> Yt[(half*4+b)*256 + c][2304]  (spatial innermost)
// ---------------------------------------------------------------------------
__global__ __launch_bounds__(256) void lnt_kernel(
    const ushort* __restrict__ Z, const ushort* __restrict__ G1,
    const ushort* __restrict__ B1, const ushort* __restrict__ G2,
    const ushort* __restrict__ B2, ushort* __restrict__ Yt)
{
    __shared__ ushort T[256][72];   // 36 KB

    const int tid = threadIdx.x;
    const int tok0 = blockIdx.x * 32;
    const int half = (tok0 >= 9216) ? 1 : 0;
    const int tr = tok0 - half * 9216;
    const int bb = tr / 2304;
    const int tokb = tr - bb * 2304;

    const int tok_l = tid >> 3;      // 0..31
    const int cq = tid & 7;          // c-chunk of 32

    const ushort* zp = Z + ((size_t)(tok0 + tok_l)) * 256 + cq * 32;
    uint dd[16];
    for (int i = 0; i < 4; i++) {
        uint4 v = *(const uint4*)(zp + i * 8);
        dd[i * 4 + 0] = v.x; dd[i * 4 + 1] = v.y;
        dd[i * 4 + 2] = v.z; dd[i * 4 + 3] = v.w;
    }
    float s = 0.f, q = 0.f;
    for (int e = 0; e < 16; e++) {
        float x0 = bf2f((ushort)dd[e]);
        float x1 = bf2f((ushort)(dd[e] >> 16));
        s += x0 + x1;
        q += x0 * x0 + x1 * x1;
    }
    s += __shfl_xor(s, 1, 64); q += __shfl_xor(q, 1, 64);
    s += __shfl_xor(s, 2, 64); q += __shfl_xor(q, 2, 64);
    s += __shfl_xor(s, 4, 64); q += __shfl_xor(q, 4, 64);
    float mu = s * (1.f / 256.f);
    float var = q * (1.f / 256.f) - mu * mu;
    float rs = rsqrtf(var + 1e-5f);

    const ushort* Gs = half ? G2 : G1;
    const ushort* Bs = half ? B2 : B1;
    const int col = tok_l + 4 * cq;          // rotation: c>>5 == cq here

    for (int i = 0; i < 4; i++) {
        int cb = cq * 32 + i * 8;
        uint4 gv = *(const uint4*)(Gs + cb);
        uint4 bv = *(const uint4*)(Bs + cb);
        uint gg[4] = {gv.x, gv.y, gv.z, gv.w};
        uint bw[4] = {bv.x, bv.y, bv.z, bv.w};
        for (int k = 0; k < 4; k++) {
            uint u = dd[i * 4 + k];
            float x0 = bf2f((ushort)u), x1 = bf2f((ushort)(u >> 16));
            float y0 = (x0 - mu) * rs * bf2f((ushort)gg[k]) + bf2f((ushort)bw[k]);
            float y1 = (x1 - mu) * rs * bf2f((ushort)(gg[k] >> 16))
                     + bf2f((ushort)(bw[k] >> 16));
            int c = cb + 2 * k;
            T[c][col]     = f2bf(y0);
            T[c + 1][col] = f2bf(y1);
        }
    }
    __syncthreads();

    // Pass 2: thread (c_row = tid>>3, tq = (tid&7)*4): 8 c rows, 4 toks each.
    const int c_row = tid >> 3;          // 0..31
    const int tq = (tid & 7) * 4;        // 0..28
    const size_t obase = ((size_t)((half * 4 + bb) * 256)) * 2304 + tokb + tq;
    for (int i = 0; i < 8; i++) {
        int c = c_row + 32 * i;          // c>>5 == i
        uint2 v = *(const uint2*)&T[c][tq + 4 * i];
        *(uint2*)(Yt + obase + (size_t)c * 2304) = v;
    }
}

// ---------------------------------------------------------------------------
// Bilinear 2x upsample from channel-major Yt[bc][48*48] (spatial contiguous).
// Each thread: one oj-pair -> float2 store.
// ---------------------------------------------------------------------------
__global__ __launch_bounds__(256) void upsample_kernel(
    const ushort* __restrict__ Yt, float* __restrict__ out)
{
    int idx = blockIdx.x * 256 + threadIdx.x;    // 36864 blocks
    int m  = idx % 48;
    int t  = idx / 48;
    int oi = t % 96;
    int bc = t / 96;                 // 0..2047

    float fi = oi * 0.5f - 0.25f;
    int i0 = (int)floorf(fi);
    float wi = fi - (float)i0;
    int i1 = i0 + 1 < 47 ? i0 + 1 : 47;
    i0 = i0 > 0 ? i0 : 0;
    int jm = m - 1 > 0 ? m - 1 : 0;
    int jp = m + 1 < 47 ? m + 1 : 47;

    const ushort* r0 = Yt + (size_t)bc * 2304 + i0 * 48;
    const ushort* r1 = Yt + (size_t)bc * 2304 + i1 * 48;
    float a0 = bf2f(r0[jm]), b0 = bf2f(r0[m]), c0 = bf2f(r0[jp]);
    float a1 = bf2f(r1[jm]), b1 = bf2f(r1[m]), c1 = bf2f(r1[jp]);
    float u = 1.f - wi;
    float ha = u * a0 + wi * a1;
    float hb = u * b0 + wi * b1;
    float hc = u * c0 + wi * c1;
    float2 o;
    o.x = 0.25f * ha + 0.75f * hb;
    o.y = 0.75f * hb + 0.25f * hc;
    *(float2*)(out + (size_t)bc * 9216 + oi * 96 + m * 2) = o;
}

// ---------------------------------------------------------------------------
extern "C" void kernel_launch(void* const* d_in, const int* in_sizes, int n_in,
                              void* d_out, int out_size, void* d_ws, size_t ws_size,
                              hipStream_t stream)
{
    (void)in_sizes; (void)n_in; (void)out_size; (void)ws_size;

    // ---- Buffer plan (stream-order-safe reuse; ~29.4 MB of ws) ----
    ushort* ws  = (ushort*)d_ws;
    ushort* Q1  = ws;                         // [9216,256]
    ushort* Q2  = Q1  + 2359296;              // contiguous with Q1
    ushort* KV1 = Q2  + 2359296;              // Kh1 + Vt1
    ushort* KV2 = KV1 + 4718592;              // Kh2 + Vt2
    ushort* wc  = KV2 + 4718592;              // canonical params
    int*    dflag = (int*)(wc + 525824);

    ushort* cqkv1w = wc;                      // [768,256] = q1w ++ kv1w
    ushort* cqkv2w = wc + 196608;             // [768,256] = q2w ++ kv2w
    ushort* cp1w  = wc + 393216;
    ushort* cp2w  = wc + 458752;
    ushort* cp1b  = wc + 524288;
    ushort* cp2b  = wc + 524544;
    ushort* cg1   = wc + 524800;
    ushort* cb1   = wc + 525056;
    ushort* cg2   = wc + 525312;
    ushort* cb2   = wc + 525568;

    float*  outf = (float*)d_out;
    ushort* O1  = (ushort*)d_out;             // bf16 staging (dead pre-upsample)
    ushort* O2  = O1 + 2359296;               // contiguous with O1
    ushort* Xb1 = O2 + 2359296;               // bf16 x1 (dead after QKV gemm)
    ushort* Xb2 = Xb1 + 2359296;              // contiguous with Xb1
    ushort* Z1  = KV2;                        // KV2 dead after attn (launch order)
    ushort* Yt  = Q1;                         // Q1+Q2 dead after attn: 9.4 MB
    (void)Q2; (void)O2; (void)Xb2;

    dim3 blk(256);
    sniff_kernel<<<dim3(1), dim3(64), 0, stream>>>((const ushort*)d_in[0], dflag);
    convert_params<<<dim3(2054), blk, 0, stream>>>(
        d_in[2], d_in[3], d_in[4], d_in[5], d_in[8], d_in[10],
        d_in[9], d_in[11], d_in[12], d_in[13], d_in[14], d_in[15],
        wc, dflag);
    convert_x<<<dim3(2304), blk, 0, stream>>>(d_in[0], d_in[1], Xb1, Xb2, dflag);

    // Merged Q+KV projections for BOTH inputs (M=18432, N=768):
    // Q scaled by scale*log2e, Kh per-head, Vt transposed.
    gemm_bt<<<dim3(288, 12), blk, 0, stream>>>(Xb1, cqkv1w, Q1, nullptr,
        18432, 768, 256, 0, dflag, 0, 1, KV1, KV1 + 2359296,
        cqkv2w, nullptr, KV2, KV2 + 2359296, 9216);

    // Both cross attentions in one dispatch. Grid (stream, qb): stream =
    // side*32+bh on blockIdx.x so each stream's 36 blocks share an XCD.
    attn_kernel<<<dim3(64, 36), dim3(128), 0, stream>>>(
        Q1, KV2, KV2 + 2359296, O1,
        Q2, KV1, KV1 + 2359296, O2);

    // Merged output projection + bias + ReLU (M=18432).
    gemm_bt<<<dim3(288, 4), blk, 0, stream>>>(O1, cp1w, Z1, cp1b,
        18432, 256, 256, 1, dflag, 0, 0, nullptr, nullptr,
        cp2w, cp2b, nullptr, nullptr, 9216);

    // LayerNorm + transpose to channel-major (18432 tokens, 32/block).
    lnt_kernel<<<dim3(576), blk, 0, stream>>>(Z1, cg1, cb1, cg2, cb2, Yt);

    // Bilinear 2x upsample into d_out (float32, both outputs, float2/thread).
    upsample_kernel<<<dim3(36864), blk, 0, stream>>>(Yt, outf);
}

// Round 10
// 303.944 us; speedup vs baseline: 1.0159x; 1.0159x over previous
//
#include <hip/hip_runtime.h>
#include <math.h>

// ---------------------------------------------------------------------------
// CrossPath: dual cross-attention block, MI355X (gfx950).
//   B=4, N=2304, C=256, H=8, D=32, out = 2 x [B,C,96,96] float32
// Inputs float32 (runtime-sniffed). Internal: bf16 MFMA, fp32 accumulation.
// R17: = R16 with ONE change: exp2f -> raw v_exp_f32 inline asm.
// R16 counters showed ~3.4x more VALU issue than the source math requires;
// the ocml exp2f wrapper (range/denormal handling around v_exp_f32) is the
// only candidate, and it has inflated EVERY attn variant so far (explains
// the stable 131-155us band across 5 structural rewrites). Scores are
// bounded (no-max softmax, |s| <~ 40), so raw v_exp_f32 with HW underflow
// is exact enough; 1 instruction instead of ~6-10.
// ---------------------------------------------------------------------------

typedef __attribute__((ext_vector_type(8))) short short8;   // 8 bf16 = 4 VGPRs
typedef __attribute__((ext_vector_type(4))) float f32x4;
typedef __attribute__((ext_vector_type(16))) float f32x16;
typedef __attribute__((ext_vector_type(2))) unsigned uint32x2;

#define MFMA16(a, b, c) __builtin_amdgcn_mfma_f32_16x16x32_bf16((a), (b), (c), 0, 0, 0)
#define MFMA32(a, b, c) __builtin_amdgcn_mfma_f32_32x32x16_bf16((a), (b), (c), 0, 0, 0)

__device__ __forceinline__ float bf2f(ushort u) {
    union { unsigned u; float f; } x; x.u = ((unsigned)u) << 16; return x.f;
}
__device__ __forceinline__ ushort f2bf(float f) {
    union { float f; unsigned u; } x; x.f = f;
    unsigned u = x.u;
    return (ushort)((u + 0x7fffu + ((u >> 16) & 1u)) >> 16);   // RNE
}
// HW packed RNE conversion: D = {bf16(b)<<16 | bf16(a)}
__device__ __forceinline__ unsigned cvt_pk_bf16(float a, float b) {
    unsigned r;
    asm("v_cvt_pk_bf16_f32 %0, %1, %2" : "=v"(r) : "v"(a), "v"(b));
    return r;
}
// Raw HW exp2: single v_exp_f32 (no ocml range-handling wrapper). Safe here:
// scores bounded, HW handles underflow->0.
__device__ __forceinline__ float fast_ex2(float x) {
    float r;
    asm("v_exp_f32 %0, %1" : "=v"(r) : "v"(x));
    return r;
}
// Exchange upper 32 lanes of a with lower 32 lanes of b (gfx950 builtin).
__device__ __forceinline__ void plswap(unsigned &a, unsigned &b) {
    uint32x2 r = __builtin_amdgcn_permlane32_swap(a, b, false, false);
    a = r[0]; b = r[1];
}

// ---------------------------------------------------------------------------
// Dtype sniffer: flag=1 means f32 inputs.
// ---------------------------------------------------------------------------
__global__ void sniff_kernel(const ushort* __restrict__ x, int* __restrict__ flag)
{
    int lane = threadIdx.x;
    ushort u = x[lane * 2];
    int e = (u >> 7) & 0xFF;
    int outlier = (e < 100 || e > 135) ? 1 : 0;
    unsigned long long m = __ballot(outlier);
    if (lane == 0) *flag = (__popcll(m) >= 16) ? 1 : 0;
}

// ---------------------------------------------------------------------------
// Canonicalize all 12 weight/param arrays to bf16 at fixed offsets in ws.
// ---------------------------------------------------------------------------
__global__ __launch_bounds__(256) void convert_params(
    const void* s0, const void* s1, const void* s2, const void* s3,
    const void* s4, const void* s5, const void* s6, const void* s7,
    const void* s8, const void* s9, const void* s10, const void* s11,
    ushort* __restrict__ dst, const int* __restrict__ flag)
{
    int idx = blockIdx.x * 256 + threadIdx.x;
    if (idx >= 525824) return;
    const void* src; int off;
    if      (idx < 65536)  { src = s0;  off = idx; }
    else if (idx < 196608) { src = s1;  off = idx - 65536; }
    else if (idx < 262144) { src = s2;  off = idx - 196608; }
    else if (idx < 393216) { src = s3;  off = idx - 262144; }
    else if (idx < 458752) { src = s4;  off = idx - 393216; }
    else if (idx < 524288) { src = s5;  off = idx - 458752; }
    else if (idx < 524544) { src = s6;  off = idx - 524288; }
    else if (idx < 524800) { src = s7;  off = idx - 524544; }
    else if (idx < 525056) { src = s8;  off = idx - 524800; }
    else if (idx < 525312) { src = s9;  off = idx - 525056; }
    else if (idx < 525568) { src = s10; off = idx - 525312; }
    else                   { src = s11; off = idx - 525568; }
    ushort v = (*flag) ? f2bf(((const float*)src)[off])
                       : ((const ushort*)src)[off];
    dst[idx] = v;
}

// ---------------------------------------------------------------------------
// Pre-convert x1/x2 -> bf16 once (8 elems/thread).
// ---------------------------------------------------------------------------
__global__ __launch_bounds__(256) void convert_x(
    const void* __restrict__ x1, const void* __restrict__ x2,
    ushort* __restrict__ o1, ushort* __restrict__ o2,
    const int* __restrict__ flag)
{
    int idx = blockIdx.x * 256 + threadIdx.x;      // 2304 blocks -> 589824 thr
    int which = idx >= 294912;
    int off = (which ? idx - 294912 : idx) * 8;
    const void* src = which ? x2 : x1;
    ushort* dst = which ? o2 : o1;
    if (*flag) {
        const float* p = (const float*)src + off;
        float4 a = *(const float4*)p;
        float4 c = *(const float4*)(p + 4);
        uint4 u;
        u.x = cvt_pk_bf16(a.x, a.y);
        u.y = cvt_pk_bf16(a.z, a.w);
        u.z = cvt_pk_bf16(c.x, c.y);
        u.w = cvt_pk_bf16(c.z, c.w);
        *(uint4*)(dst + off) = u;
    } else {
        *(uint4*)(dst + off) = *(const uint4*)((const ushort*)src + off);
    }
}

// ---------------------------------------------------------------------------
// GEMM: C[M,N] = A[M,K]*W[N,K]^T, bf16 MFMA 16x16x32, tile 64x64, 4 waves.
// Two stacked problems (rows [0,mhalf) use W/bias/Kh/Vt, rows [mhalf,M) use
// W2/bias2/Kh2/Vt2). mode 0: plain C (+bias/relu). mode 1 (merged QKV,
// N=768): col<256 -> Q row-major SCALED by scale*log2e; col<512 ->
// Kh[b][h][tok][32]; else -> Vt[b][h][d][2304].
// ---------------------------------------------------------------------------
__global__ __launch_bounds__(256) void gemm_bt(
    const void* __restrict__ Ain, const ushort* __restrict__ W,
    ushort* __restrict__ C, const ushort* __restrict__ bias,
    int M, int N, int K, int relu, const int* __restrict__ dflag, int a_ext,
    int mode, ushort* __restrict__ Kh, ushort* __restrict__ Vt,
    const ushort* __restrict__ W2, const ushort* __restrict__ bias2,
    ushort* __restrict__ Kh2, ushort* __restrict__ Vt2, int mhalf)
{
    __shared__ __align__(16) ushort As[64][40];
    __shared__ __align__(16) ushort Ws[64][40];

    const int m0 = blockIdx.x * 64;
    const int n0 = blockIdx.y * 64;
    const int tid = threadIdx.x;
    const int w = tid >> 6;
    const int lane = tid & 63;
    const int lm = lane & 15;
    const int quad = lane >> 4;
    const int a32 = a_ext ? *dflag : 0;

    const int side = (mhalf && m0 >= mhalf) ? 1 : 0;
    const ushort* Wu = side ? W2 : W;
    const ushort* bu = side ? bias2 : bias;
    ushort* Khu = side ? Kh2 : Kh;
    ushort* Vtu = side ? Vt2 : Vt;

    const f32x4 Z4 = {0.f, 0.f, 0.f, 0.f};
    f32x4 acc[4];
    for (int j = 0; j < 4; j++) acc[j] = Z4;

    const ushort* A16 = (const ushort*)Ain;
    const float*  A32 = (const float*)Ain;
    const int row = tid >> 2, off = (tid & 3) * 8;

    for (int k0 = 0; k0 < K; k0 += 32) {
        __syncthreads();
        if (a32) {
            const float* p0 = A32 + (size_t)(m0 + row) * K + k0 + off;
            float4 f0 = *(const float4*)p0;
            float4 f1 = *(const float4*)(p0 + 4);
            uint4 t0;
            t0.x = cvt_pk_bf16(f0.x, f0.y);
            t0.y = cvt_pk_bf16(f0.z, f0.w);
            t0.z = cvt_pk_bf16(f1.x, f1.y);
            t0.w = cvt_pk_bf16(f1.z, f1.w);
            *(uint4*)&As[row][off] = t0;
        } else {
            *(uint4*)&As[row][off] =
                *(const uint4*)(A16 + (size_t)(m0 + row) * K + k0 + off);
        }
        *(uint4*)&Ws[row][off] =
            *(const uint4*)(Wu + (size_t)(n0 + row) * K + k0 + off);
        __syncthreads();

        short8 af = *(const short8*)&As[w * 16 + lm][quad * 8];
        for (int nt = 0; nt < 4; nt++) {
            short8 wf = *(const short8*)&Ws[nt * 16 + lm][quad * 8];
            acc[nt] = MFMA16(af, wf, acc[nt]);
        }
    }

    const int grow = m0 + w * 16 + quad * 4;     // global C row (4 consecutive)
    const int grel = grow - (side ? mhalf : 0);  // row within half (Kh/Vt)
    if (mode == 1) {
        const float QSC = 0.17677669529663687f * 1.4426950408889634f;
        int bb = grel / 2304;
        int tok = grel - bb * 2304;              // 4-aligned; same bb for r=0..3
        for (int nt = 0; nt < 4; nt++) {
            int col = n0 + nt * 16 + lm;
            if (col < 256) {
                for (int r = 0; r < 4; r++)
                    C[(size_t)(grow + r) * 256 + col] = f2bf(acc[nt][r] * QSC);
            } else if (col < 512) {
                int c2 = col - 256, hh = c2 >> 5, d = c2 & 31;
                for (int r = 0; r < 4; r++)
                    Khu[(((size_t)bb * 8 + hh) * 2304 + tok + r) * 32 + d] = f2bf(acc[nt][r]);
            } else {
                int c2 = col - 512, hh = c2 >> 5, d = c2 & 31;
                uint2 o;
                o.x = cvt_pk_bf16(acc[nt][0], acc[nt][1]);
                o.y = cvt_pk_bf16(acc[nt][2], acc[nt][3]);
                *(uint2*)&Vtu[(((size_t)bb * 8 + hh) * 32 + d) * 2304 + tok] = o;
            }
        }
    } else {
        for (int nt = 0; nt < 4; nt++) {
            int col = n0 + nt * 16 + lm;
            float bv = bu ? bf2f(bu[col]) : 0.f;
            for (int r = 0; r < 4; r++) {
                float v = acc[nt][r] + bv;
                if (relu) v = fmaxf(v, 0.f);
                C[(size_t)(grow + r) * N + col] = f2bf(v);
            }
        }
    }
}

// ---------------------------------------------------------------------------
// Flash cross-attention, S^T form on 32x32x16 MFMA, no-max softmax
// (p = exp2(s) via raw v_exp_f32, Q pre-scaled by scale*log2e in QKV GEMM).
// NO LDS, NO BARRIERS: K/V fragments load directly from global (streams are
// L2-resident; full 64B-line utilization). 2-tile register prefetch (sets
// A/B). Block = 2 independent waves x 32 q. Grid (stream=64, qb=36) keeps
// a stream's 36 blocks on one XCD.
// Q:[B,2304,256]; Kh:[b][h][tok][32]; Vt:[b][h][d][2304]; O:[B,2304,256].
// ---------------------------------------------------------------------------
__global__ __launch_bounds__(128) void attn_kernel(
    const ushort* __restrict__ Qa, const ushort* __restrict__ Kha,
    const ushort* __restrict__ Vta, ushort* __restrict__ Oa,
    const ushort* __restrict__ Qb, const ushort* __restrict__ Khb2,
    const ushort* __restrict__ Vtb2, ushort* __restrict__ Ob)
{
    const int sid = blockIdx.x;           // 0..63: side*32 + bh (XCD-affine)
    const int qb = blockIdx.y;            // 0..35: 64-q tile
    const int side = sid >> 5;
    const int bh = sid & 31;
    const ushort* Q  = side ? Qb   : Qa;
    const ushort* Kh = side ? Khb2 : Kha;
    const ushort* Vt = side ? Vtb2 : Vta;
    ushort* O        = side ? Ob   : Oa;

    const int b = bh >> 3, h = bh & 7;
    const int tid = threadIdx.x;
    const int w = tid >> 6, lane = tid & 63;
    const int l31 = lane & 31, hl = lane >> 5;

    // Q B-frags: lane holds q-col = l31, d = 16*dstep + hl*8 + j (persistent)
    const int qrow = qb * 64 + w * 32 + l31;
    const ushort* qp = Q + ((size_t)b * 2304 + qrow) * 256 + h * 32 + hl * 8;
    const short8 qf0 = *(const short8*)qp;          // d = hl*8 + j
    const short8 qf1 = *(const short8*)(qp + 16);   // d = 16 + hl*8 + j

    f32x16 o0, o1;
    #pragma unroll
    for (int i = 0; i < 16; i++) { o0[i] = 0.f; o1[i] = 0.f; }
    const f32x16 Z16 = o0;
    float l = 0.f;

    // Per-lane fragment base pointers (direct-from-global).
    // K-frag of 32-key tile t: lane reads Kh[tok=t*32+l31][d=hl*8+j].
    // V-frag of tile t: lane reads Vt[d=l31][tok=t*32+hl*8+j].
    const ushort* kp0 = Kh + (size_t)bh * 2304 * 32 + (size_t)l31 * 32 + hl * 8;
    const ushort* vp0 = Vt + (size_t)bh * 32 * 2304 + (size_t)l31 * 2304 + hl * 8;

#define LOADT(kf0v, kf1v, vf0v, vf1v, t) { \
    const ushort* _kp = kp0 + (size_t)(t) * 1024; \
    kf0v = *(const short8*)_kp; \
    kf1v = *(const short8*)(_kp + 16); \
    const ushort* _vp = vp0 + (t) * 32; \
    vf0v = *(const short8*)_vp; \
    vf1v = *(const short8*)(_vp + 16); \
}
    // One 32-key tile from registers: S^T MFMA pair -> exp2 -> pack/swap ->
    // PV MFMA pair. No LDS, no barriers.
#define COMP(kf0v, kf1v, vf0v, vf1v, oacc) { \
    f32x16 s = MFMA32(kf0v, qf0, Z16); \
    s = MFMA32(kf1v, qf1, s); \
    float p[16]; \
    _Pragma("unroll") \
    for (int i = 0; i < 16; i++) p[i] = fast_ex2(s[i]); \
    l += (((p[0] + p[1]) + (p[2] + p[3])) + ((p[4] + p[5]) + (p[6] + p[7]))) \
       + (((p[8] + p[9]) + (p[10] + p[11])) + ((p[12] + p[13]) + (p[14] + p[15]))); \
    unsigned c0 = cvt_pk_bf16(p[0],  p[1]); \
    unsigned c1 = cvt_pk_bf16(p[2],  p[3]); \
    unsigned c2 = cvt_pk_bf16(p[4],  p[5]); \
    unsigned c3 = cvt_pk_bf16(p[6],  p[7]); \
    unsigned c4 = cvt_pk_bf16(p[8],  p[9]); \
    unsigned c5 = cvt_pk_bf16(p[10], p[11]); \
    unsigned c6 = cvt_pk_bf16(p[12], p[13]); \
    unsigned c7 = cvt_pk_bf16(p[14], p[15]); \
    plswap(c0, c2); plswap(c1, c3); plswap(c4, c6); plswap(c5, c7); \
    union { unsigned u[4]; short8 s8; } pA, pB; \
    pA.u[0] = c0; pA.u[1] = c1; pA.u[2] = c2; pA.u[3] = c3; \
    pB.u[0] = c4; pB.u[1] = c5; pB.u[2] = c6; pB.u[3] = c7; \
    oacc = MFMA32(vf0v, pA.s8, oacc); \
    oacc = MFMA32(vf1v, pB.s8, oacc); \
}

    short8 ka0, ka1, va0, va1;    // set A: even tiles
    short8 kb0, kb1, vb0, vb1;    // set B: odd tiles

    LOADT(ka0, ka1, va0, va1, 0);
    LOADT(kb0, kb1, vb0, vb1, 1);

    for (int t = 0; t < 72; t += 2) {
        COMP(ka0, ka1, va0, va1, o0);             // tile t
        { int ta = t + 2 < 72 ? t + 2 : 70; LOADT(ka0, ka1, va0, va1, ta); }
        COMP(kb0, kb1, vb0, vb1, o1);             // tile t+1
        { int tb = t + 3 < 72 ? t + 3 : 71; LOADT(kb0, kb1, vb0, vb1, tb); }
    }
#undef LOADT
#undef COMP

    // Lane halves hold disjoint key subsets for the same q: reduce l.
    l += __shfl_xor(l, 32, 64);
    float rl = 1.f / l;
    // o reg r: d = (r&3) + 8*(r>>2) + 4*hl, q = l31.
    ushort* op = O + ((size_t)b * 2304 + qrow) * 256 + h * 32 + hl * 4;
    #pragma unroll
    for (int g = 0; g < 4; g++) {
        float e0 = (o0[4 * g]     + o1[4 * g])     * rl;
        float e1 = (o0[4 * g + 1] + o1[4 * g + 1]) * rl;
        float e2 = (o0[4 * g + 2] + o1[4 * g + 2]) * rl;
        float e3 = (o0[4 * g + 3] + o1[4 * g + 3]) * rl;
        uint2 o;
        o.x = cvt_pk_bf16(e0, e1);
        o.y = cvt_pk_bf16(e2, e3);
        *(uint2*)(op + 8 * g) = o;
    }
}

// ---------------------------------------------------------------------------
// LayerNorm over C=256 fused with transpose to channel-major:
//   Z[18432][256] -> Yt[(half*4+b)*256 + c][2304]  (spatial innermost)
// ---------------------------------------------------------------------------
__global__ __launch_bounds__(256) void lnt_kernel(
    const ushort* __restrict__ Z, const ushort* __restrict__ G1,
    const ushort* __restrict__ B1, const ushort* __restrict__ G2,
    const ushort* __restrict__ B2, ushort* __restrict__ Yt)
{
    __shared__ ushort T[256][72];   // 36 KB

    const int tid = threadIdx.x;
    const int tok0 = blockIdx.x * 32;
    const int half = (tok0 >= 9216) ? 1 : 0;
    const int tr = tok0 - half * 9216;
    const int bb = tr / 2304;
    const int tokb = tr - bb * 2304;

    const int tok_l = tid >> 3;      // 0..31
    const int cq = tid & 7;          // c-chunk of 32

    const ushort* zp = Z + ((size_t)(tok0 + tok_l)) * 256 + cq * 32;
    uint dd[16];
    for (int i = 0; i < 4; i++) {
        uint4 v = *(const uint4*)(zp + i * 8);
        dd[i * 4 + 0] = v.x; dd[i * 4 + 1] = v.y;
        dd[i * 4 + 2] = v.z; dd[i * 4 + 3] = v.w;
    }
    float s = 0.f, q = 0.f;
    for (int e = 0; e < 16; e++) {
        float x0 = bf2f((ushort)dd[e]);
        float x1 = bf2f((ushort)(dd[e] >> 16));
        s += x0 + x1;
        q += x0 * x0 + x1 * x1;
    }
    s += __shfl_xor(s, 1, 64); q += __shfl_xor(q, 1, 64);
    s += __shfl_xor(s, 2, 64); q += __shfl_xor(q, 2, 64);
    s += __shfl_xor(s, 4, 64); q += __shfl_xor(q, 4, 64);
    float mu = s * (1.f / 256.f);
    float var = q * (1.f / 256.f) - mu * mu;
    float rs = rsqrtf(var + 1e-5f);

    const ushort* Gs = half ? G2 : G1;
    const ushort* Bs = half ? B2 : B1;
    const int col = tok_l + 4 * cq;          // rotation: c>>5 == cq here

    for (int i = 0; i < 4; i++) {
        int cb = cq * 32 + i * 8;
        uint4 gv = *(const uint4*)(Gs + cb);
        uint4 bv = *(const uint4*)(Bs + cb);
        uint gg[4] = {gv.x, gv.y, gv.z, gv.w};
        uint bw[4] = {bv.x, bv.y, bv.z, bv.w};
        for (int k = 0; k < 4; k++) {
            uint u = dd[i * 4 + k];
            float x0 = bf2f((ushort)u), x1 = bf2f((ushort)(u >> 16));
            float y0 = (x0 - mu) * rs * bf2f((ushort)gg[k]) + bf2f((ushort)bw[k]);
            float y1 = (x1 - mu) * rs * bf2f((ushort)(gg[k] >> 16))
                     + bf2f((ushort)(bw[k] >> 16));
            int c = cb + 2 * k;
            T[c][col]     = f2bf(y0);
            T[c + 1][col] = f2bf(y1);
        }
    }
    __syncthreads();

    // Pass 2: thread (c_row = tid>>3, tq = (tid&7)*4): 8 c rows, 4 toks each.
    const int c_row = tid >> 3;          // 0..31
    const int tq = (tid & 7) * 4;        // 0..28
    const size_t obase = ((size_t)((half * 4 + bb) * 256)) * 2304 + tokb + tq;
    for (int i = 0; i < 8; i++) {
        int c = c_row + 32 * i;          // c>>5 == i
        uint2 v = *(const uint2*)&T[c][tq + 4 * i];
        *(uint2*)(Yt + obase + (size_t)c * 2304) = v;
    }
}

// ---------------------------------------------------------------------------
// Bilinear 2x upsample from channel-major Yt[bc][48*48] (spatial contiguous).
// Each thread: one oj-pair -> float2 store.
// ---------------------------------------------------------------------------
__global__ __launch_bounds__(256) void upsample_kernel(
    const ushort* __restrict__ Yt, float* __restrict__ out)
{
    int idx = blockIdx.x * 256 + threadIdx.x;    // 36864 blocks
    int m  = idx % 48;
    int t  = idx / 48;
    int oi = t % 96;
    int bc = t / 96;                 // 0..2047

    float fi = oi * 0.5f - 0.25f;
    int i0 = (int)floorf(fi);
    float wi = fi - (float)i0;
    int i1 = i0 + 1 < 47 ? i0 + 1 : 47;
    i0 = i0 > 0 ? i0 : 0;
    int jm = m - 1 > 0 ? m - 1 : 0;
    int jp = m + 1 < 47 ? m + 1 : 47;

    const ushort* r0 = Yt + (size_t)bc * 2304 + i0 * 48;
    const ushort* r1 = Yt + (size_t)bc * 2304 + i1 * 48;
    float a0 = bf2f(r0[jm]), b0 = bf2f(r0[m]), c0 = bf2f(r0[jp]);
    float a1 = bf2f(r1[jm]), b1 = bf2f(r1[m]), c1 = bf2f(r1[jp]);
    float u = 1.f - wi;
    float ha = u * a0 + wi * a1;
    float hb = u * b0 + wi * b1;
    float hc = u * c0 + wi * c1;
    float2 o;
    o.x = 0.25f * ha + 0.75f * hb;
    o.y = 0.75f * hb + 0.25f * hc;
    *(float2*)(out + (size_t)bc * 9216 + oi * 96 + m * 2) = o;
}

// ---------------------------------------------------------------------------
extern "C" void kernel_launch(void* const* d_in, const int* in_sizes, int n_in,
                              void* d_out, int out_size, void* d_ws, size_t ws_size,
                              hipStream_t stream)
{
    (void)in_sizes; (void)n_in; (void)out_size; (void)ws_size;

    // ---- Buffer plan (stream-order-safe reuse; ~29.4 MB of ws) ----
    ushort* ws  = (ushort*)d_ws;
    ushort* Q1  = ws;                         // [9216,256]
    ushort* Q2  = Q1  + 2359296;              // contiguous with Q1
    ushort* KV1 = Q2  + 2359296;              // Kh1 + Vt1
    ushort* KV2 = KV1 + 4718592;              // Kh2 + Vt2
    ushort* wc  = KV2 + 4718592;              // canonical params
    int*    dflag = (int*)(wc + 525824);

    ushort* cqkv1w = wc;                      // [768,256] = q1w ++ kv1w
    ushort* cqkv2w = wc + 196608;             // [768,256] = q2w ++ kv2w
    ushort* cp1w  = wc + 393216;
    ushort* cp2w  = wc + 458752;
    ushort* cp1b  = wc + 524288;
    ushort* cp2b  = wc + 524544;
    ushort* cg1   = wc + 524800;
    ushort* cb1   = wc + 525056;
    ushort* cg2   = wc + 525312;
    ushort* cb2   = wc + 525568;

    float*  outf = (float*)d_out;
    ushort* O1  = (ushort*)d_out;             // bf16 staging (dead pre-upsample)
    ushort* O2  = O1 + 2359296;               // contiguous with O1
    ushort* Xb1 = O2 + 2359296;               // bf16 x1 (dead after QKV gemm)
    ushort* Xb2 = Xb1 + 2359296;              // contiguous with Xb1
    ushort* Z1  = KV2;                        // KV2 dead after attn (launch order)
    ushort* Yt  = Q1;                         // Q1+Q2 dead after attn: 9.4 MB
    (void)Q2; (void)O2; (void)Xb2;

    dim3 blk(256);
    sniff_kernel<<<dim3(1), dim3(64), 0, stream>>>((const ushort*)d_in[0], dflag);
    convert_params<<<dim3(2054), blk, 0, stream>>>(
        d_in[2], d_in[3], d_in[4], d_in[5], d_in[8], d_in[10],
        d_in[9], d_in[11], d_in[12], d_in[13], d_in[14], d_in[15],
        wc, dflag);
    convert_x<<<dim3(2304), blk, 0, stream>>>(d_in[0], d_in[1], Xb1, Xb2, dflag);

    // Merged Q+KV projections for BOTH inputs (M=18432, N=768):
    // Q scaled by scale*log2e, Kh per-head, Vt transposed.
    gemm_bt<<<dim3(288, 12), blk, 0, stream>>>(Xb1, cqkv1w, Q1, nullptr,
        18432, 768, 256, 0, dflag, 0, 1, KV1, KV1 + 2359296,
        cqkv2w, nullptr, KV2, KV2 + 2359296, 9216);

    // Both cross attentions in one dispatch. Grid (stream, qb): stream =
    // side*32+bh on blockIdx.x so each stream's 36 blocks share an XCD.
    attn_kernel<<<dim3(64, 36), dim3(128), 0, stream>>>(
        Q1, KV2, KV2 + 2359296, O1,
        Q2, KV1, KV1 + 2359296, O2);

    // Merged output projection + bias + ReLU (M=18432).
    gemm_bt<<<dim3(288, 4), blk, 0, stream>>>(O1, cp1w, Z1, cp1b,
        18432, 256, 256, 1, dflag, 0, 0, nullptr, nullptr,
        cp2w, cp2b, nullptr, nullptr, 9216);

    // LayerNorm + transpose to channel-major (18432 tokens, 32/block).
    lnt_kernel<<<dim3(576), blk, 0, stream>>>(Z1, cg1, cb1, cg2, cb2, Yt);

    // Bilinear 2x upsample into d_out (float32, both outputs, float2/thread).
    upsample_kernel<<<dim3(36864), blk, 0, stream>>>(Yt, outf);
}

// Round 12
// 284.271 us; speedup vs baseline: 1.0862x; 1.0692x over previous
//
#include <hip/hip_runtime.h>
#include <math.h>

// ---------------------------------------------------------------------------
// CrossPath: dual cross-attention block, MI355X (gfx950).
//   B=4, N=2304, C=256, H=8, D=32, out = 2 x [B,C,96,96] float32
// Inputs float32 (runtime-sniffed). Internal: bf16 MFMA, fp32 accumulation.
// R19: = R18 with the K4 reader stride fixed (writer: tile block = 1024
// ushorts, dh at +512; R18's attn read t*2048/+1024 -> wrong tiles,
// absmax 6.05). Structure unchanged:
//  (1) Tiled K4[bh][t32][dh][tok32][d16] / V4[bh][kt16][d32][k16] layouts
//      (written by QKV-GEMM epilogue): every K/V fragment load is one
//      contiguous 1KB wave-block, 100% line utilization.
//  (2) 64 q per wave (two Q-sets + two accumulators): each K/V fragment
//      feeds 8 MFMAs instead of 4.
//  Keeps: no LDS, no barriers, raw v_exp_f32, XCD-affine grid (64,18).
// ---------------------------------------------------------------------------

typedef __attribute__((ext_vector_type(8))) short short8;   // 8 bf16 = 4 VGPRs
typedef __attribute__((ext_vector_type(4))) float f32x4;
typedef __attribute__((ext_vector_type(16))) float f32x16;
typedef __attribute__((ext_vector_type(2))) unsigned uint32x2;

#define MFMA16(a, b, c) __builtin_amdgcn_mfma_f32_16x16x32_bf16((a), (b), (c), 0, 0, 0)
#define MFMA32(a, b, c) __builtin_amdgcn_mfma_f32_32x32x16_bf16((a), (b), (c), 0, 0, 0)

__device__ __forceinline__ float bf2f(ushort u) {
    union { unsigned u; float f; } x; x.u = ((unsigned)u) << 16; return x.f;
}
__device__ __forceinline__ ushort f2bf(float f) {
    union { float f; unsigned u; } x; x.f = f;
    unsigned u = x.u;
    return (ushort)((u + 0x7fffu + ((u >> 16) & 1u)) >> 16);   // RNE
}
// HW packed RNE conversion: D = {bf16(b)<<16 | bf16(a)}
__device__ __forceinline__ unsigned cvt_pk_bf16(float a, float b) {
    unsigned r;
    asm("v_cvt_pk_bf16_f32 %0, %1, %2" : "=v"(r) : "v"(a), "v"(b));
    return r;
}
// Raw HW exp2: single v_exp_f32 (no ocml wrapper). Scores bounded; HW
// underflow->0 is correct here.
__device__ __forceinline__ float fast_ex2(float x) {
    float r;
    asm("v_exp_f32 %0, %1" : "=v"(r) : "v"(x));
    return r;
}
// Exchange upper 32 lanes of a with lower 32 lanes of b (gfx950 builtin).
__device__ __forceinline__ void plswap(unsigned &a, unsigned &b) {
    uint32x2 r = __builtin_amdgcn_permlane32_swap(a, b, false, false);
    a = r[0]; b = r[1];
}

// ---------------------------------------------------------------------------
// Dtype sniffer: flag=1 means f32 inputs.
// ---------------------------------------------------------------------------
__global__ void sniff_kernel(const ushort* __restrict__ x, int* __restrict__ flag)
{
    int lane = threadIdx.x;
    ushort u = x[lane * 2];
    int e = (u >> 7) & 0xFF;
    int outlier = (e < 100 || e > 135) ? 1 : 0;
    unsigned long long m = __ballot(outlier);
    if (lane == 0) *flag = (__popcll(m) >= 16) ? 1 : 0;
}

// ---------------------------------------------------------------------------
// Canonicalize all 12 weight/param arrays to bf16 at fixed offsets in ws.
// ---------------------------------------------------------------------------
__global__ __launch_bounds__(256) void convert_params(
    const void* s0, const void* s1, const void* s2, const void* s3,
    const void* s4, const void* s5, const void* s6, const void* s7,
    const void* s8, const void* s9, const void* s10, const void* s11,
    ushort* __restrict__ dst, const int* __restrict__ flag)
{
    int idx = blockIdx.x * 256 + threadIdx.x;
    if (idx >= 525824) return;
    const void* src; int off;
    if      (idx < 65536)  { src = s0;  off = idx; }
    else if (idx < 196608) { src = s1;  off = idx - 65536; }
    else if (idx < 262144) { src = s2;  off = idx - 196608; }
    else if (idx < 393216) { src = s3;  off = idx - 262144; }
    else if (idx < 458752) { src = s4;  off = idx - 393216; }
    else if (idx < 524288) { src = s5;  off = idx - 458752; }
    else if (idx < 524544) { src = s6;  off = idx - 524288; }
    else if (idx < 524800) { src = s7;  off = idx - 524544; }
    else if (idx < 525056) { src = s8;  off = idx - 524800; }
    else if (idx < 525312) { src = s9;  off = idx - 525056; }
    else if (idx < 525568) { src = s10; off = idx - 525312; }
    else                   { src = s11; off = idx - 525568; }
    ushort v = (*flag) ? f2bf(((const float*)src)[off])
                       : ((const ushort*)src)[off];
    dst[idx] = v;
}

// ---------------------------------------------------------------------------
// Pre-convert x1/x2 -> bf16 once (8 elems/thread).
// ---------------------------------------------------------------------------
__global__ __launch_bounds__(256) void convert_x(
    const void* __restrict__ x1, const void* __restrict__ x2,
    ushort* __restrict__ o1, ushort* __restrict__ o2,
    const int* __restrict__ flag)
{
    int idx = blockIdx.x * 256 + threadIdx.x;      // 2304 blocks -> 589824 thr
    int which = idx >= 294912;
    int off = (which ? idx - 294912 : idx) * 8;
    const void* src = which ? x2 : x1;
    ushort* dst = which ? o2 : o1;
    if (*flag) {
        const float* p = (const float*)src + off;
        float4 a = *(const float4*)p;
        float4 c = *(const float4*)(p + 4);
        uint4 u;
        u.x = cvt_pk_bf16(a.x, a.y);
        u.y = cvt_pk_bf16(a.z, a.w);
        u.z = cvt_pk_bf16(c.x, c.y);
        u.w = cvt_pk_bf16(c.z, c.w);
        *(uint4*)(dst + off) = u;
    } else {
        *(uint4*)(dst + off) = *(const uint4*)((const ushort*)src + off);
    }
}

// ---------------------------------------------------------------------------
// GEMM: C[M,N] = A[M,K]*W[N,K]^T, bf16 MFMA 16x16x32, tile 64x64, 4 waves.
// Two stacked problems (rows [0,mhalf) use W/.../Kh/Vt, rows [mhalf,M) use
// W2/.../Kh2/Vt2). mode 0: plain C (+bias/relu). mode 1 (merged QKV, N=768):
//   col<256  -> Q row-major SCALED by scale*log2e
//   col<512  -> K4[bh][t32=72][dh=2][tok32=32][d16=16]  (tile block = 1024)
//   else     -> V4[bh][kt16=144][d=32][k16=16]          (kt block = 512)
// ---------------------------------------------------------------------------
__global__ __launch_bounds__(256) void gemm_bt(
    const void* __restrict__ Ain, const ushort* __restrict__ W,
    ushort* __restrict__ C, const ushort* __restrict__ bias,
    int M, int N, int K, int relu, const int* __restrict__ dflag, int a_ext,
    int mode, ushort* __restrict__ Kh, ushort* __restrict__ Vt,
    const ushort* __restrict__ W2, const ushort* __restrict__ bias2,
    ushort* __restrict__ Kh2, ushort* __restrict__ Vt2, int mhalf)
{
    __shared__ __align__(16) ushort As[64][40];
    __shared__ __align__(16) ushort Ws[64][40];

    const int m0 = blockIdx.x * 64;
    const int n0 = blockIdx.y * 64;
    const int tid = threadIdx.x;
    const int w = tid >> 6;
    const int lane = tid & 63;
    const int lm = lane & 15;
    const int quad = lane >> 4;
    const int a32 = a_ext ? *dflag : 0;

    const int side = (mhalf && m0 >= mhalf) ? 1 : 0;
    const ushort* Wu = side ? W2 : W;
    const ushort* bu = side ? bias2 : bias;
    ushort* Khu = side ? Kh2 : Kh;
    ushort* Vtu = side ? Vt2 : Vt;

    const f32x4 Z4 = {0.f, 0.f, 0.f, 0.f};
    f32x4 acc[4];
    for (int j = 0; j < 4; j++) acc[j] = Z4;

    const ushort* A16 = (const ushort*)Ain;
    const float*  A32 = (const float*)Ain;
    const int row = tid >> 2, off = (tid & 3) * 8;

    for (int k0 = 0; k0 < K; k0 += 32) {
        __syncthreads();
        if (a32) {
            const float* p0 = A32 + (size_t)(m0 + row) * K + k0 + off;
            float4 f0 = *(const float4*)p0;
            float4 f1 = *(const float4*)(p0 + 4);
            uint4 t0;
            t0.x = cvt_pk_bf16(f0.x, f0.y);
            t0.y = cvt_pk_bf16(f0.z, f0.w);
            t0.z = cvt_pk_bf16(f1.x, f1.y);
            t0.w = cvt_pk_bf16(f1.z, f1.w);
            *(uint4*)&As[row][off] = t0;
        } else {
            *(uint4*)&As[row][off] =
                *(const uint4*)(A16 + (size_t)(m0 + row) * K + k0 + off);
        }
        *(uint4*)&Ws[row][off] =
            *(const uint4*)(Wu + (size_t)(n0 + row) * K + k0 + off);
        __syncthreads();

        short8 af = *(const short8*)&As[w * 16 + lm][quad * 8];
        for (int nt = 0; nt < 4; nt++) {
            short8 wf = *(const short8*)&Ws[nt * 16 + lm][quad * 8];
            acc[nt] = MFMA16(af, wf, acc[nt]);
        }
    }

    const int grow = m0 + w * 16 + quad * 4;     // global C row (4 consecutive)
    const int grel = grow - (side ? mhalf : 0);  // row within half (Kh/Vt)
    if (mode == 1) {
        const float QSC = 0.17677669529663687f * 1.4426950408889634f;
        int bb = grel / 2304;
        int tok = grel - bb * 2304;              // 4-aligned; same bb for r=0..3
        for (int nt = 0; nt < 4; nt++) {
            int col = n0 + nt * 16 + lm;
            if (col < 256) {
                for (int r = 0; r < 4; r++)
                    C[(size_t)(grow + r) * 256 + col] = f2bf(acc[nt][r] * QSC);
            } else if (col < 512) {
                int c2 = col - 256, hh = c2 >> 5, d = c2 & 31;
                // K4: [(bb*8+hh)][t32=tok>>5][dh=d>>4][tok&31][d&15]
                size_t kb = ((size_t)(bb * 8 + hh) * 72 + (tok >> 5)) * 1024
                          + (size_t)(d >> 4) * 512 + (size_t)(d & 15);
                for (int r = 0; r < 4; r++)
                    Khu[kb + (size_t)((tok + r) & 31) * 16] = f2bf(acc[nt][r]);
            } else {
                int c2 = col - 512, hh = c2 >> 5, d = c2 & 31;
                // V4: [(bb*8+hh)][kt=tok>>4][d][tok&15]; 4 toks contiguous
                size_t vb = ((size_t)(bb * 8 + hh) * 144 + (tok >> 4)) * 512
                          + (size_t)d * 16 + (size_t)(tok & 15);
                uint2 o;
                o.x = cvt_pk_bf16(acc[nt][0], acc[nt][1]);
                o.y = cvt_pk_bf16(acc[nt][2], acc[nt][3]);
                *(uint2*)&Vtu[vb] = o;
            }
        }
    } else {
        for (int nt = 0; nt < 4; nt++) {
            int col = n0 + nt * 16 + lm;
            float bv = bu ? bf2f(bu[col]) : 0.f;
            for (int r = 0; r < 4; r++) {
                float v = acc[nt][r] + bv;
                if (relu) v = fmaxf(v, 0.f);
                C[(size_t)(grow + r) * N + col] = f2bf(v);
            }
        }
    }
}

// ---------------------------------------------------------------------------
// Flash cross-attention, S^T form on 32x32x16 MFMA, no-max softmax
// (p = exp2(s) via raw v_exp_f32, Q pre-scaled by scale*log2e in QKV GEMM).
// NO LDS, NO BARRIERS. K4/V4 tiled layouts: for tile t (32 keys),
//   kf0 = K4 + t*1024 + l31*16 + hl*8, kf1 = +512   (d halves)
//   vf0 = V4 + t*1024 + l31*16 + hl*8, vf1 = +512   (key halves)
// 64 q per wave (two Q-sets share each K/V fragment -> 8 MFMAs per 4
// loads). 2-tile register prefetch (sets A/B). Block = 2 waves (128 q).
// Grid (stream=64, qb=18), XCD-affine.
// Q:[B,2304,256]; K4/V4: see gemm_bt; O:[B,2304,256].
// ---------------------------------------------------------------------------
__global__ __launch_bounds__(128) void attn_kernel(
    const ushort* __restrict__ Qa, const ushort* __restrict__ Kha,
    const ushort* __restrict__ Vta, ushort* __restrict__ Oa,
    const ushort* __restrict__ Qb, const ushort* __restrict__ Khb2,
    const ushort* __restrict__ Vtb2, ushort* __restrict__ Ob)
{
    const int sid = blockIdx.x;           // 0..63: side*32 + bh (XCD-affine)
    const int qb = blockIdx.y;            // 0..17: 128-q tile
    const int side = sid >> 5;
    const int bh = sid & 31;
    const ushort* Q  = side ? Qb   : Qa;
    const ushort* Kh = side ? Khb2 : Kha;
    const ushort* Vt = side ? Vtb2 : Vta;
    ushort* O        = side ? Ob   : Oa;

    const int b = bh >> 3, h = bh & 7;
    const int tid = threadIdx.x;
    const int w = tid >> 6, lane = tid & 63;
    const int l31 = lane & 31, hl = lane >> 5;

    // Two Q-sets per wave: q rows qb*128 + w*64 + {l31, 32+l31}
    const int qrow0 = qb * 128 + w * 64 + l31;
    const int qrow1 = qrow0 + 32;
    const ushort* qp0 = Q + ((size_t)b * 2304 + qrow0) * 256 + h * 32 + hl * 8;
    const ushort* qp1 = Q + ((size_t)b * 2304 + qrow1) * 256 + h * 32 + hl * 8;
    const short8 qf0a = *(const short8*)qp0;          // d = hl*8 + j
    const short8 qf1a = *(const short8*)(qp0 + 16);   // d = 16 + hl*8 + j
    const short8 qf0b = *(const short8*)qp1;
    const short8 qf1b = *(const short8*)(qp1 + 16);

    f32x16 oa, ob;
    #pragma unroll
    for (int i = 0; i < 16; i++) { oa[i] = 0.f; ob[i] = 0.f; }
    const f32x16 Z16 = oa;
    float la = 0.f, lb = 0.f;

    // Fragment base pointers (contiguous 1KB per wave per load pair).
    const ushort* kp0 = Kh + (size_t)bh * 73728 + l31 * 16 + hl * 8;
    const ushort* vp0 = Vt + (size_t)bh * 73728 + l31 * 16 + hl * 8;

#define LOADT(kf0v, kf1v, vf0v, vf1v, t) { \
    const ushort* _kp = kp0 + (size_t)(t) * 1024; \
    kf0v = *(const short8*)_kp; \
    kf1v = *(const short8*)(_kp + 512); \
    const ushort* _vp = vp0 + (size_t)(t) * 1024; \
    vf0v = *(const short8*)_vp; \
    vf1v = *(const short8*)(_vp + 512); \
}
    // One 32-key tile for one q-set: S^T pair -> exp2 -> pack/swap -> PV pair.
#define QSET(kf0v, kf1v, vf0v, vf1v, qf0v, qf1v, oacc, lacc) { \
    f32x16 s = MFMA32(kf0v, qf0v, Z16); \
    s = MFMA32(kf1v, qf1v, s); \
    float p[16]; \
    _Pragma("unroll") \
    for (int i = 0; i < 16; i++) p[i] = fast_ex2(s[i]); \
    lacc += (((p[0] + p[1]) + (p[2] + p[3])) + ((p[4] + p[5]) + (p[6] + p[7]))) \
          + (((p[8] + p[9]) + (p[10] + p[11])) + ((p[12] + p[13]) + (p[14] + p[15]))); \
    unsigned c0 = cvt_pk_bf16(p[0],  p[1]); \
    unsigned c1 = cvt_pk_bf16(p[2],  p[3]); \
    unsigned c2 = cvt_pk_bf16(p[4],  p[5]); \
    unsigned c3 = cvt_pk_bf16(p[6],  p[7]); \
    unsigned c4 = cvt_pk_bf16(p[8],  p[9]); \
    unsigned c5 = cvt_pk_bf16(p[10], p[11]); \
    unsigned c6 = cvt_pk_bf16(p[12], p[13]); \
    unsigned c7 = cvt_pk_bf16(p[14], p[15]); \
    plswap(c0, c2); plswap(c1, c3); plswap(c4, c6); plswap(c5, c7); \
    union { unsigned u[4]; short8 s8; } pA, pB; \
    pA.u[0] = c0; pA.u[1] = c1; pA.u[2] = c2; pA.u[3] = c3; \
    pB.u[0] = c4; pB.u[1] = c5; pB.u[2] = c6; pB.u[3] = c7; \
    oacc = MFMA32(vf0v, pA.s8, oacc); \
    oacc = MFMA32(vf1v, pB.s8, oacc); \
}
#define COMP(kf0v, kf1v, vf0v, vf1v) { \
    QSET(kf0v, kf1v, vf0v, vf1v, qf0a, qf1a, oa, la); \
    QSET(kf0v, kf1v, vf0v, vf1v, qf0b, qf1b, ob, lb); \
}

    short8 kA0, kA1, vA0, vA1;    // set A: even tiles
    short8 kB0, kB1, vB0, vB1;    // set B: odd tiles

    LOADT(kA0, kA1, vA0, vA1, 0);
    LOADT(kB0, kB1, vB0, vB1, 1);

    for (int t = 0; t < 72; t += 2) {
        COMP(kA0, kA1, vA0, vA1);                 // tile t
        { int ta = t + 2 < 72 ? t + 2 : 70; LOADT(kA0, kA1, vA0, vA1, ta); }
        COMP(kB0, kB1, vB0, vB1);                 // tile t+1
        { int tb = t + 3 < 72 ? t + 3 : 71; LOADT(kB0, kB1, vB0, vB1, tb); }
    }
#undef LOADT
#undef QSET
#undef COMP

    // Lane halves hold disjoint key subsets for the same q: reduce l.
    la += __shfl_xor(la, 32, 64);
    lb += __shfl_xor(lb, 32, 64);
    float ra = 1.f / la, rb = 1.f / lb;
    // o reg r: d = (r&3) + 8*(r>>2) + 4*hl, q = l31 (set a) / 32+l31 (set b).
    ushort* op0 = O + ((size_t)b * 2304 + qrow0) * 256 + h * 32 + hl * 4;
    ushort* op1 = O + ((size_t)b * 2304 + qrow1) * 256 + h * 32 + hl * 4;
    #pragma unroll
    for (int g = 0; g < 4; g++) {
        uint2 o;
        o.x = cvt_pk_bf16(oa[4 * g] * ra, oa[4 * g + 1] * ra);
        o.y = cvt_pk_bf16(oa[4 * g + 2] * ra, oa[4 * g + 3] * ra);
        *(uint2*)(op0 + 8 * g) = o;
        uint2 o2;
        o2.x = cvt_pk_bf16(ob[4 * g] * rb, ob[4 * g + 1] * rb);
        o2.y = cvt_pk_bf16(ob[4 * g + 2] * rb, ob[4 * g + 3] * rb);
        *(uint2*)(op1 + 8 * g) = o2;
    }
}

// ---------------------------------------------------------------------------
// LayerNorm over C=256 fused with transpose to channel-major:
//   Z[18432][256] -> Yt[(half*4+b)*256 + c][2304]  (spatial innermost)
// ---------------------------------------------------------------------------
__global__ __launch_bounds__(256) void lnt_kernel(
    const ushort* __restrict__ Z, const ushort* __restrict__ G1,
    const ushort* __restrict__ B1, const ushort* __restrict__ G2,
    const ushort* __restrict__ B2, ushort* __restrict__ Yt)
{
    __shared__ ushort T[256][72];   // 36 KB

    const int tid = threadIdx.x;
    const int tok0 = blockIdx.x * 32;
    const int half = (tok0 >= 9216) ? 1 : 0;
    const int tr = tok0 - half * 9216;
    const int bb = tr / 2304;
    const int tokb = tr - bb * 2304;

    const int tok_l = tid >> 3;      // 0..31
    const int cq = tid & 7;          // c-chunk of 32

    const ushort* zp = Z + ((size_t)(tok0 + tok_l)) * 256 + cq * 32;
    uint dd[16];
    for (int i = 0; i < 4; i++) {
        uint4 v = *(const uint4*)(zp + i * 8);
        dd[i * 4 + 0] = v.x; dd[i * 4 + 1] = v.y;
        dd[i * 4 + 2] = v.z; dd[i * 4 + 3] = v.w;
    }
    float s = 0.f, q = 0.f;
    for (int e = 0; e < 16; e++) {
        float x0 = bf2f((ushort)dd[e]);
        float x1 = bf2f((ushort)(dd[e] >> 16));
        s += x0 + x1;
        q += x0 * x0 + x1 * x1;
    }
    s += __shfl_xor(s, 1, 64); q += __shfl_xor(q, 1, 64);
    s += __shfl_xor(s, 2, 64); q += __shfl_xor(q, 2, 64);
    s += __shfl_xor(s, 4, 64); q += __shfl_xor(q, 4, 64);
    float mu = s * (1.f / 256.f);
    float var = q * (1.f / 256.f) - mu * mu;
    float rs = rsqrtf(var + 1e-5f);

    const ushort* Gs = half ? G2 : G1;
    const ushort* Bs = half ? B2 : B1;
    const int col = tok_l + 4 * cq;          // rotation: c>>5 == cq here

    for (int i = 0; i < 4; i++) {
        int cb = cq * 32 + i * 8;
        uint4 gv = *(const uint4*)(Gs + cb);
        uint4 bv = *(const uint4*)(Bs + cb);
        uint gg[4] = {gv.x, gv.y, gv.z, gv.w};
        uint bw[4] = {bv.x, bv.y, bv.z, bv.w};
        for (int k = 0; k < 4; k++) {
            uint u = dd[i * 4 + k];
            float x0 = bf2f((ushort)u), x1 = bf2f((ushort)(u >> 16));
            float y0 = (x0 - mu) * rs * bf2f((ushort)gg[k]) + bf2f((ushort)bw[k]);
            float y1 = (x1 - mu) * rs * bf2f((ushort)(gg[k] >> 16))
                     + bf2f((ushort)(bw[k] >> 16));
            int c = cb + 2 * k;
            T[c][col]     = f2bf(y0);
            T[c + 1][col] = f2bf(y1);
        }
    }
    __syncthreads();

    // Pass 2: thread (c_row = tid>>3, tq = (tid&7)*4): 8 c rows, 4 toks each.
    const int c_row = tid >> 3;          // 0..31
    const int tq = (tid & 7) * 4;        // 0..28
    const size_t obase = ((size_t)((half * 4 + bb) * 256)) * 2304 + tokb + tq;
    for (int i = 0; i < 8; i++) {
        int c = c_row + 32 * i;          // c>>5 == i
        uint2 v = *(const uint2*)&T[c][tq + 4 * i];
        *(uint2*)(Yt + obase + (size_t)c * 2304) = v;
    }
}

// ---------------------------------------------------------------------------
// Bilinear 2x upsample from channel-major Yt[bc][48*48] (spatial contiguous).
// Each thread: one oj-pair -> float2 store.
// ---------------------------------------------------------------------------
__global__ __launch_bounds__(256) void upsample_kernel(
    const ushort* __restrict__ Yt, float* __restrict__ out)
{
    int idx = blockIdx.x * 256 + threadIdx.x;    // 36864 blocks
    int m  = idx % 48;
    int t  = idx / 48;
    int oi = t % 96;
    int bc = t / 96;                 // 0..2047

    float fi = oi * 0.5f - 0.25f;
    int i0 = (int)floorf(fi);
    float wi = fi - (float)i0;
    int i1 = i0 + 1 < 47 ? i0 + 1 : 47;
    i0 = i0 > 0 ? i0 : 0;
    int jm = m - 1 > 0 ? m - 1 : 0;
    int jp = m + 1 < 47 ? m + 1 : 47;

    const ushort* r0 = Yt + (size_t)bc * 2304 + i0 * 48;
    const ushort* r1 = Yt + (size_t)bc * 2304 + i1 * 48;
    float a0 = bf2f(r0[jm]), b0 = bf2f(r0[m]), c0 = bf2f(r0[jp]);
    float a1 = bf2f(r1[jm]), b1 = bf2f(r1[m]), c1 = bf2f(r1[jp]);
    float u = 1.f - wi;
    float ha = u * a0 + wi * a1;
    float hb = u * b0 + wi * b1;
    float hc = u * c0 + wi * c1;
    float2 o;
    o.x = 0.25f * ha + 0.75f * hb;
    o.y = 0.75f * hb + 0.25f * hc;
    *(float2*)(out + (size_t)bc * 9216 + oi * 96 + m * 2) = o;
}

// ---------------------------------------------------------------------------
extern "C" void kernel_launch(void* const* d_in, const int* in_sizes, int n_in,
                              void* d_out, int out_size, void* d_ws, size_t ws_size,
                              hipStream_t stream)
{
    (void)in_sizes; (void)n_in; (void)out_size; (void)ws_size;

    // ---- Buffer plan (stream-order-safe reuse; ~29.4 MB of ws) ----
    ushort* ws  = (ushort*)d_ws;
    ushort* Q1  = ws;                         // [9216,256]
    ushort* Q2  = Q1  + 2359296;              // contiguous with Q1
    ushort* KV1 = Q2  + 2359296;              // K4_1 + V4_1
    ushort* KV2 = KV1 + 4718592;              // K4_2 + V4_2
    ushort* wc  = KV2 + 4718592;              // canonical params
    int*    dflag = (int*)(wc + 525824);

    ushort* cqkv1w = wc;                      // [768,256] = q1w ++ kv1w
    ushort* cqkv2w = wc + 196608;             // [768,256] = q2w ++ kv2w
    ushort* cp1w  = wc + 393216;
    ushort* cp2w  = wc + 458752;
    ushort* cp1b  = wc + 524288;
    ushort* cp2b  = wc + 524544;
    ushort* cg1   = wc + 524800;
    ushort* cb1   = wc + 525056;
    ushort* cg2   = wc + 525312;
    ushort* cb2   = wc + 525568;

    float*  outf = (float*)d_out;
    ushort* O1  = (ushort*)d_out;             // bf16 staging (dead pre-upsample)
    ushort* O2  = O1 + 2359296;               // contiguous with O1
    ushort* Xb1 = O2 + 2359296;               // bf16 x1 (dead after QKV gemm)
    ushort* Xb2 = Xb1 + 2359296;              // contiguous with Xb1
    ushort* Z1  = KV2;                        // KV2 dead after attn (launch order)
    ushort* Yt  = Q1;                         // Q1+Q2 dead after attn: 9.4 MB
    (void)Q2; (void)O2; (void)Xb2;

    dim3 blk(256);
    sniff_kernel<<<dim3(1), dim3(64), 0, stream>>>((const ushort*)d_in[0], dflag);
    convert_params<<<dim3(2054), blk, 0, stream>>>(
        d_in[2], d_in[3], d_in[4], d_in[5], d_in[8], d_in[10],
        d_in[9], d_in[11], d_in[12], d_in[13], d_in[14], d_in[15],
        wc, dflag);
    convert_x<<<dim3(2304), blk, 0, stream>>>(d_in[0], d_in[1], Xb1, Xb2, dflag);

    // Merged Q+KV projections for BOTH inputs (M=18432, N=768):
    // Q scaled by scale*log2e, K4/V4 tiled layouts.
    gemm_bt<<<dim3(288, 12), blk, 0, stream>>>(Xb1, cqkv1w, Q1, nullptr,
        18432, 768, 256, 0, dflag, 0, 1, KV1, KV1 + 2359296,
        cqkv2w, nullptr, KV2, KV2 + 2359296, 9216);

    // Both cross attentions in one dispatch. Grid (stream, qb): stream =
    // side*32+bh on blockIdx.x so each stream's 18 blocks share an XCD.
    attn_kernel<<<dim3(64, 18), dim3(128), 0, stream>>>(
        Q1, KV2, KV2 + 2359296, O1,
        Q2, KV1, KV1 + 2359296, O2);

    // Merged output projection + bias + ReLU (M=18432).
    gemm_bt<<<dim3(288, 4), blk, 0, stream>>>(O1, cp1w, Z1, cp1b,
        18432, 256, 256, 1, dflag, 0, 0, nullptr, nullptr,
        cp2w, cp2b, nullptr, nullptr, 9216);

    // LayerNorm + transpose to channel-major (18432 tokens, 32/block).
    lnt_kernel<<<dim3(576), blk, 0, stream>>>(Z1, cg1, cb1, cg2, cb2, Yt);

    // Bilinear 2x upsample into d_out (float32, both outputs, float2/thread).
    upsample_kernel<<<dim3(36864), blk, 0, stream>>>(Yt, outf);
}

// Round 13
// 247.161 us; speedup vs baseline: 1.2493x; 1.1501x over previous
//
#include <hip/hip_runtime.h>
#include <math.h>

// ---------------------------------------------------------------------------
// CrossPath: dual cross-attention block, MI355X (gfx950).
//   B=4, N=2304, C=256, H=8, D=32, out = 2 x [B,C,96,96] float32
// Inputs float32 (runtime-sniffed). Internal: bf16 MFMA, fp32 accumulation.
// R20: split-K attention. R19 counters: occupancy 12.8% (~1 wave/SIMD) ->
// dependent chains fully exposed. Now block = 4 waves / 64 q; wave w does
// key-tiles [w*18, w*18+18) only (serial chain 4x shorter; 9216 waves
// total). Unnormalized partials (o,l) combined in-block via LDS (exact:
// no-max softmax partials are linear). Keeps K4/V4 contiguous-fragment
// layouts, no barriers in the K-loop, raw v_exp_f32, XCD-affine grid.
// ---------------------------------------------------------------------------

typedef __attribute__((ext_vector_type(8))) short short8;   // 8 bf16 = 4 VGPRs
typedef __attribute__((ext_vector_type(4))) float f32x4;
typedef __attribute__((ext_vector_type(16))) float f32x16;
typedef __attribute__((ext_vector_type(2))) unsigned uint32x2;

#define MFMA16(a, b, c) __builtin_amdgcn_mfma_f32_16x16x32_bf16((a), (b), (c), 0, 0, 0)
#define MFMA32(a, b, c) __builtin_amdgcn_mfma_f32_32x32x16_bf16((a), (b), (c), 0, 0, 0)

__device__ __forceinline__ float bf2f(ushort u) {
    union { unsigned u; float f; } x; x.u = ((unsigned)u) << 16; return x.f;
}
__device__ __forceinline__ ushort f2bf(float f) {
    union { float f; unsigned u; } x; x.f = f;
    unsigned u = x.u;
    return (ushort)((u + 0x7fffu + ((u >> 16) & 1u)) >> 16);   // RNE
}
// HW packed RNE conversion: D = {bf16(b)<<16 | bf16(a)}
__device__ __forceinline__ unsigned cvt_pk_bf16(float a, float b) {
    unsigned r;
    asm("v_cvt_pk_bf16_f32 %0, %1, %2" : "=v"(r) : "v"(a), "v"(b));
    return r;
}
// Raw HW exp2: single v_exp_f32 (no ocml wrapper). Scores bounded; HW
// underflow->0 is correct here.
__device__ __forceinline__ float fast_ex2(float x) {
    float r;
    asm("v_exp_f32 %0, %1" : "=v"(r) : "v"(x));
    return r;
}
// Exchange upper 32 lanes of a with lower 32 lanes of b (gfx950 builtin).
__device__ __forceinline__ void plswap(unsigned &a, unsigned &b) {
    uint32x2 r = __builtin_amdgcn_permlane32_swap(a, b, false, false);
    a = r[0]; b = r[1];
}

// ---------------------------------------------------------------------------
// Dtype sniffer: flag=1 means f32 inputs.
// ---------------------------------------------------------------------------
__global__ void sniff_kernel(const ushort* __restrict__ x, int* __restrict__ flag)
{
    int lane = threadIdx.x;
    ushort u = x[lane * 2];
    int e = (u >> 7) & 0xFF;
    int outlier = (e < 100 || e > 135) ? 1 : 0;
    unsigned long long m = __ballot(outlier);
    if (lane == 0) *flag = (__popcll(m) >= 16) ? 1 : 0;
}

// ---------------------------------------------------------------------------
// Canonicalize all 12 weight/param arrays to bf16 at fixed offsets in ws.
// ---------------------------------------------------------------------------
__global__ __launch_bounds__(256) void convert_params(
    const void* s0, const void* s1, const void* s2, const void* s3,
    const void* s4, const void* s5, const void* s6, const void* s7,
    const void* s8, const void* s9, const void* s10, const void* s11,
    ushort* __restrict__ dst, const int* __restrict__ flag)
{
    int idx = blockIdx.x * 256 + threadIdx.x;
    if (idx >= 525824) return;
    const void* src; int off;
    if      (idx < 65536)  { src = s0;  off = idx; }
    else if (idx < 196608) { src = s1;  off = idx - 65536; }
    else if (idx < 262144) { src = s2;  off = idx - 196608; }
    else if (idx < 393216) { src = s3;  off = idx - 262144; }
    else if (idx < 458752) { src = s4;  off = idx - 393216; }
    else if (idx < 524288) { src = s5;  off = idx - 458752; }
    else if (idx < 524544) { src = s6;  off = idx - 524288; }
    else if (idx < 524800) { src = s7;  off = idx - 524544; }
    else if (idx < 525056) { src = s8;  off = idx - 524800; }
    else if (idx < 525312) { src = s9;  off = idx - 525056; }
    else if (idx < 525568) { src = s10; off = idx - 525312; }
    else                   { src = s11; off = idx - 525568; }
    ushort v = (*flag) ? f2bf(((const float*)src)[off])
                       : ((const ushort*)src)[off];
    dst[idx] = v;
}

// ---------------------------------------------------------------------------
// Pre-convert x1/x2 -> bf16 once (8 elems/thread).
// ---------------------------------------------------------------------------
__global__ __launch_bounds__(256) void convert_x(
    const void* __restrict__ x1, const void* __restrict__ x2,
    ushort* __restrict__ o1, ushort* __restrict__ o2,
    const int* __restrict__ flag)
{
    int idx = blockIdx.x * 256 + threadIdx.x;      // 2304 blocks -> 589824 thr
    int which = idx >= 294912;
    int off = (which ? idx - 294912 : idx) * 8;
    const void* src = which ? x2 : x1;
    ushort* dst = which ? o2 : o1;
    if (*flag) {
        const float* p = (const float*)src + off;
        float4 a = *(const float4*)p;
        float4 c = *(const float4*)(p + 4);
        uint4 u;
        u.x = cvt_pk_bf16(a.x, a.y);
        u.y = cvt_pk_bf16(a.z, a.w);
        u.z = cvt_pk_bf16(c.x, c.y);
        u.w = cvt_pk_bf16(c.z, c.w);
        *(uint4*)(dst + off) = u;
    } else {
        *(uint4*)(dst + off) = *(const uint4*)((const ushort*)src + off);
    }
}

// ---------------------------------------------------------------------------
// GEMM: C[M,N] = A[M,K]*W[N,K]^T, bf16 MFMA 16x16x32, tile 64x64, 4 waves.
// Two stacked problems (rows [0,mhalf) use W/.../Kh/Vt, rows [mhalf,M) use
// W2/.../Kh2/Vt2). mode 0: plain C (+bias/relu). mode 1 (merged QKV, N=768):
//   col<256  -> Q row-major SCALED by scale*log2e
//   col<512  -> K4[bh][t32=72][dh=2][tok32=32][d16=16]  (tile block = 1024)
//   else     -> V4[bh][kt16=144][d=32][k16=16]          (kt block = 512)
// ---------------------------------------------------------------------------
__global__ __launch_bounds__(256) void gemm_bt(
    const void* __restrict__ Ain, const ushort* __restrict__ W,
    ushort* __restrict__ C, const ushort* __restrict__ bias,
    int M, int N, int K, int relu, const int* __restrict__ dflag, int a_ext,
    int mode, ushort* __restrict__ Kh, ushort* __restrict__ Vt,
    const ushort* __restrict__ W2, const ushort* __restrict__ bias2,
    ushort* __restrict__ Kh2, ushort* __restrict__ Vt2, int mhalf)
{
    __shared__ __align__(16) ushort As[64][40];
    __shared__ __align__(16) ushort Ws[64][40];

    const int m0 = blockIdx.x * 64;
    const int n0 = blockIdx.y * 64;
    const int tid = threadIdx.x;
    const int w = tid >> 6;
    const int lane = tid & 63;
    const int lm = lane & 15;
    const int quad = lane >> 4;
    const int a32 = a_ext ? *dflag : 0;

    const int side = (mhalf && m0 >= mhalf) ? 1 : 0;
    const ushort* Wu = side ? W2 : W;
    const ushort* bu = side ? bias2 : bias;
    ushort* Khu = side ? Kh2 : Kh;
    ushort* Vtu = side ? Vt2 : Vt;

    const f32x4 Z4 = {0.f, 0.f, 0.f, 0.f};
    f32x4 acc[4];
    for (int j = 0; j < 4; j++) acc[j] = Z4;

    const ushort* A16 = (const ushort*)Ain;
    const float*  A32 = (const float*)Ain;
    const int row = tid >> 2, off = (tid & 3) * 8;

    for (int k0 = 0; k0 < K; k0 += 32) {
        __syncthreads();
        if (a32) {
            const float* p0 = A32 + (size_t)(m0 + row) * K + k0 + off;
            float4 f0 = *(const float4*)p0;
            float4 f1 = *(const float4*)(p0 + 4);
            uint4 t0;
            t0.x = cvt_pk_bf16(f0.x, f0.y);
            t0.y = cvt_pk_bf16(f0.z, f0.w);
            t0.z = cvt_pk_bf16(f1.x, f1.y);
            t0.w = cvt_pk_bf16(f1.z, f1.w);
            *(uint4*)&As[row][off] = t0;
        } else {
            *(uint4*)&As[row][off] =
                *(const uint4*)(A16 + (size_t)(m0 + row) * K + k0 + off);
        }
        *(uint4*)&Ws[row][off] =
            *(const uint4*)(Wu + (size_t)(n0 + row) * K + k0 + off);
        __syncthreads();

        short8 af = *(const short8*)&As[w * 16 + lm][quad * 8];
        for (int nt = 0; nt < 4; nt++) {
            short8 wf = *(const short8*)&Ws[nt * 16 + lm][quad * 8];
            acc[nt] = MFMA16(af, wf, acc[nt]);
        }
    }

    const int grow = m0 + w * 16 + quad * 4;     // global C row (4 consecutive)
    const int grel = grow - (side ? mhalf : 0);  // row within half (Kh/Vt)
    if (mode == 1) {
        const float QSC = 0.17677669529663687f * 1.4426950408889634f;
        int bb = grel / 2304;
        int tok = grel - bb * 2304;              // 4-aligned; same bb for r=0..3
        for (int nt = 0; nt < 4; nt++) {
            int col = n0 + nt * 16 + lm;
            if (col < 256) {
                for (int r = 0; r < 4; r++)
                    C[(size_t)(grow + r) * 256 + col] = f2bf(acc[nt][r] * QSC);
            } else if (col < 512) {
                int c2 = col - 256, hh = c2 >> 5, d = c2 & 31;
                // K4: [(bb*8+hh)][t32=tok>>5][dh=d>>4][tok&31][d&15]
                size_t kb = ((size_t)(bb * 8 + hh) * 72 + (tok >> 5)) * 1024
                          + (size_t)(d >> 4) * 512 + (size_t)(d & 15);
                for (int r = 0; r < 4; r++)
                    Khu[kb + (size_t)((tok + r) & 31) * 16] = f2bf(acc[nt][r]);
            } else {
                int c2 = col - 512, hh = c2 >> 5, d = c2 & 31;
                // V4: [(bb*8+hh)][kt=tok>>4][d][tok&15]; 4 toks contiguous
                size_t vb = ((size_t)(bb * 8 + hh) * 144 + (tok >> 4)) * 512
                          + (size_t)d * 16 + (size_t)(tok & 15);
                uint2 o;
                o.x = cvt_pk_bf16(acc[nt][0], acc[nt][1]);
                o.y = cvt_pk_bf16(acc[nt][2], acc[nt][3]);
                *(uint2*)&Vtu[vb] = o;
            }
        }
    } else {
        for (int nt = 0; nt < 4; nt++) {
            int col = n0 + nt * 16 + lm;
            float bv = bu ? bf2f(bu[col]) : 0.f;
            for (int r = 0; r < 4; r++) {
                float v = acc[nt][r] + bv;
                if (relu) v = fmaxf(v, 0.f);
                C[(size_t)(grow + r) * N + col] = f2bf(v);
            }
        }
    }
}

// ---------------------------------------------------------------------------
// Flash cross-attention, S^T form on 32x32x16 MFMA, no-max softmax
// (p = exp2(s) via raw v_exp_f32, Q pre-scaled by scale*log2e in QKV GEMM).
// Split-K: block = 4 waves / 64 q; wave w processes key-tiles
// [w*18, w*18+18). Unnormalized (o,l) partials combined in-block via LDS
// (one __syncthreads; waves 0/1 normalize+store qset a/b).
// K4/V4 tiled layouts: tile t -> kf at t*1024 (+512 for d-half),
// vf at t*1024 (+512 for key-half); each load = contiguous 1KB wave-block.
// 2-tile register prefetch in the K-loop (no barriers there).
// Grid (stream=64, qb=36), XCD-affine.
// Q:[B,2304,256]; K4/V4: see gemm_bt; O:[B,2304,256].
// ---------------------------------------------------------------------------
__global__ __launch_bounds__(256) void attn_kernel(
    const ushort* __restrict__ Qa, const ushort* __restrict__ Kha,
    const ushort* __restrict__ Vta, ushort* __restrict__ Oa,
    const ushort* __restrict__ Qb, const ushort* __restrict__ Khb2,
    const ushort* __restrict__ Vtb2, ushort* __restrict__ Ob)
{
    __shared__ float Lo[4][2][64][16];   // 32 KB partial O
    __shared__ float Ll[4][2][64];       //  2 KB partial l

    const int sid = blockIdx.x;           // 0..63: side*32 + bh (XCD-affine)
    const int qb = blockIdx.y;            // 0..35: 64-q tile
    const int side = sid >> 5;
    const int bh = sid & 31;
    const ushort* Q  = side ? Qb   : Qa;
    const ushort* Kh = side ? Khb2 : Kha;
    const ushort* Vt = side ? Vtb2 : Vta;
    ushort* O        = side ? Ob   : Oa;

    const int b = bh >> 3, h = bh & 7;
    const int tid = threadIdx.x;
    const int w = tid >> 6, lane = tid & 63;
    const int l31 = lane & 31, hl = lane >> 5;

    // Block-level q rows (same for all waves): qset a = qb*64 + l31,
    // qset b = +32.
    const int qrow0 = qb * 64 + l31;
    const int qrow1 = qrow0 + 32;
    const ushort* qp0 = Q + ((size_t)b * 2304 + qrow0) * 256 + h * 32 + hl * 8;
    const ushort* qp1 = Q + ((size_t)b * 2304 + qrow1) * 256 + h * 32 + hl * 8;
    const short8 qf0a = *(const short8*)qp0;          // d = hl*8 + j
    const short8 qf1a = *(const short8*)(qp0 + 16);   // d = 16 + hl*8 + j
    const short8 qf0b = *(const short8*)qp1;
    const short8 qf1b = *(const short8*)(qp1 + 16);

    f32x16 oa, ob;
    #pragma unroll
    for (int i = 0; i < 16; i++) { oa[i] = 0.f; ob[i] = 0.f; }
    const f32x16 Z16 = oa;
    float la = 0.f, lb = 0.f;

    // Fragment base pointers (contiguous 1KB per wave per load pair).
    const ushort* kp0 = Kh + (size_t)bh * 73728 + l31 * 16 + hl * 8;
    const ushort* vp0 = Vt + (size_t)bh * 73728 + l31 * 16 + hl * 8;

#define LOADT(kf0v, kf1v, vf0v, vf1v, t) { \
    const ushort* _kp = kp0 + (size_t)(t) * 1024; \
    kf0v = *(const short8*)_kp; \
    kf1v = *(const short8*)(_kp + 512); \
    const ushort* _vp = vp0 + (size_t)(t) * 1024; \
    vf0v = *(const short8*)_vp; \
    vf1v = *(const short8*)(_vp + 512); \
}
    // One 32-key tile for one q-set: S^T pair -> exp2 -> pack/swap -> PV pair.
#define QSET(kf0v, kf1v, vf0v, vf1v, qf0v, qf1v, oacc, lacc) { \
    f32x16 s = MFMA32(kf0v, qf0v, Z16); \
    s = MFMA32(kf1v, qf1v, s); \
    float p[16]; \
    _Pragma("unroll") \
    for (int i = 0; i < 16; i++) p[i] = fast_ex2(s[i]); \
    lacc += (((p[0] + p[1]) + (p[2] + p[3])) + ((p[4] + p[5]) + (p[6] + p[7]))) \
          + (((p[8] + p[9]) + (p[10] + p[11])) + ((p[12] + p[13]) + (p[14] + p[15]))); \
    unsigned c0 = cvt_pk_bf16(p[0],  p[1]); \
    unsigned c1 = cvt_pk_bf16(p[2],  p[3]); \
    unsigned c2 = cvt_pk_bf16(p[4],  p[5]); \
    unsigned c3 = cvt_pk_bf16(p[6],  p[7]); \
    unsigned c4 = cvt_pk_bf16(p[8],  p[9]); \
    unsigned c5 = cvt_pk_bf16(p[10], p[11]); \
    unsigned c6 = cvt_pk_bf16(p[12], p[13]); \
    unsigned c7 = cvt_pk_bf16(p[14], p[15]); \
    plswap(c0, c2); plswap(c1, c3); plswap(c4, c6); plswap(c5, c7); \
    union { unsigned u[4]; short8 s8; } pA, pB; \
    pA.u[0] = c0; pA.u[1] = c1; pA.u[2] = c2; pA.u[3] = c3; \
    pB.u[0] = c4; pB.u[1] = c5; pB.u[2] = c6; pB.u[3] = c7; \
    oacc = MFMA32(vf0v, pA.s8, oacc); \
    oacc = MFMA32(vf1v, pB.s8, oacc); \
}
#define COMP(kf0v, kf1v, vf0v, vf1v) { \
    QSET(kf0v, kf1v, vf0v, vf1v, qf0a, qf1a, oa, la); \
    QSET(kf0v, kf1v, vf0v, vf1v, qf0b, qf1b, ob, lb); \
}

    short8 kA0, kA1, vA0, vA1;    // set A: even local tiles
    short8 kB0, kB1, vB0, vB1;    // set B: odd local tiles

    const int t0 = w * 18;                        // this wave's first tile

    LOADT(kA0, kA1, vA0, vA1, t0);
    LOADT(kB0, kB1, vB0, vB1, t0 + 1);

    for (int i = 0; i < 9; i++) {                 // local tiles 2i, 2i+1
        COMP(kA0, kA1, vA0, vA1);                 // tile t0+2i
        { int ta = t0 + 2 * i + 2; ta = ta < 72 ? ta : 70;
          LOADT(kA0, kA1, vA0, vA1, ta); }
        COMP(kB0, kB1, vB0, vB1);                 // tile t0+2i+1
        { int tb = t0 + 2 * i + 3; tb = tb < 72 ? tb : 71;
          LOADT(kB0, kB1, vB0, vB1, tb); }
    }
#undef LOADT
#undef QSET
#undef COMP

    // Intra-wave: lane halves hold disjoint key subsets -> reduce l.
    la += __shfl_xor(la, 32, 64);
    lb += __shfl_xor(lb, 32, 64);

    // Publish partials; combine across the 4 key-range waves.
    #pragma unroll
    for (int r = 0; r < 16; r++) {
        Lo[w][0][lane][r] = oa[r];
        Lo[w][1][lane][r] = ob[r];
    }
    Ll[w][0][lane] = la;
    Ll[w][1][lane] = lb;
    __syncthreads();

    if (w < 2) {                                  // wave w combines qset w
        float os[16];
        #pragma unroll
        for (int r = 0; r < 16; r++) os[r] = 0.f;
        float ls = 0.f;
        #pragma unroll
        for (int u = 0; u < 4; u++) {
            ls += Ll[u][w][lane];
            #pragma unroll
            for (int r = 0; r < 16; r++) os[r] += Lo[u][w][lane][r];
        }
        float rl = 1.f / ls;
        // o reg r: d = (r&3) + 8*(r>>2) + 4*hl, q = l31 (+32 for qset b).
        const int qrow = (w == 0) ? qrow0 : qrow1;
        ushort* op = O + ((size_t)b * 2304 + qrow) * 256 + h * 32 + hl * 4;
        #pragma unroll
        for (int g = 0; g < 4; g++) {
            uint2 o;
            o.x = cvt_pk_bf16(os[4 * g] * rl, os[4 * g + 1] * rl);
            o.y = cvt_pk_bf16(os[4 * g + 2] * rl, os[4 * g + 3] * rl);
            *(uint2*)(op + 8 * g) = o;
        }
    }
}

// ---------------------------------------------------------------------------
// LayerNorm over C=256 fused with transpose to channel-major:
//   Z[18432][256] -> Yt[(half*4+b)*256 + c][2304]  (spatial innermost)
// ---------------------------------------------------------------------------
__global__ __launch_bounds__(256) void lnt_kernel(
    const ushort* __restrict__ Z, const ushort* __restrict__ G1,
    const ushort* __restrict__ B1, const ushort* __restrict__ G2,
    const ushort* __restrict__ B2, ushort* __restrict__ Yt)
{
    __shared__ ushort T[256][72];   // 36 KB

    const int tid = threadIdx.x;
    const int tok0 = blockIdx.x * 32;
    const int half = (tok0 >= 9216) ? 1 : 0;
    const int tr = tok0 - half * 9216;
    const int bb = tr / 2304;
    const int tokb = tr - bb * 2304;

    const int tok_l = tid >> 3;      // 0..31
    const int cq = tid & 7;          // c-chunk of 32

    const ushort* zp = Z + ((size_t)(tok0 + tok_l)) * 256 + cq * 32;
    uint dd[16];
    for (int i = 0; i < 4; i++) {
        uint4 v = *(const uint4*)(zp + i * 8);
        dd[i * 4 + 0] = v.x; dd[i * 4 + 1] = v.y;
        dd[i * 4 + 2] = v.z; dd[i * 4 + 3] = v.w;
    }
    float s = 0.f, q = 0.f;
    for (int e = 0; e < 16; e++) {
        float x0 = bf2f((ushort)dd[e]);
        float x1 = bf2f((ushort)(dd[e] >> 16));
        s += x0 + x1;
        q += x0 * x0 + x1 * x1;
    }
    s += __shfl_xor(s, 1, 64); q += __shfl_xor(q, 1, 64);
    s += __shfl_xor(s, 2, 64); q += __shfl_xor(q, 2, 64);
    s += __shfl_xor(s, 4, 64); q += __shfl_xor(q, 4, 64);
    float mu = s * (1.f / 256.f);
    float var = q * (1.f / 256.f) - mu * mu;
    float rs = rsqrtf(var + 1e-5f);

    const ushort* Gs = half ? G2 : G1;
    const ushort* Bs = half ? B2 : B1;
    const int col = tok_l + 4 * cq;          // rotation: c>>5 == cq here

    for (int i = 0; i < 4; i++) {
        int cb = cq * 32 + i * 8;
        uint4 gv = *(const uint4*)(Gs + cb);
        uint4 bv = *(const uint4*)(Bs + cb);
        uint gg[4] = {gv.x, gv.y, gv.z, gv.w};
        uint bw[4] = {bv.x, bv.y, bv.z, bv.w};
        for (int k = 0; k < 4; k++) {
            uint u = dd[i * 4 + k];
            float x0 = bf2f((ushort)u), x1 = bf2f((ushort)(u >> 16));
            float y0 = (x0 - mu) * rs * bf2f((ushort)gg[k]) + bf2f((ushort)bw[k]);
            float y1 = (x1 - mu) * rs * bf2f((ushort)(gg[k] >> 16))
                     + bf2f((ushort)(bw[k] >> 16));
            int c = cb + 2 * k;
            T[c][col]     = f2bf(y0);
            T[c + 1][col] = f2bf(y1);
        }
    }
    __syncthreads();

    // Pass 2: thread (c_row = tid>>3, tq = (tid&7)*4): 8 c rows, 4 toks each.
    const int c_row = tid >> 3;          // 0..31
    const int tq = (tid & 7) * 4;        // 0..28
    const size_t obase = ((size_t)((half * 4 + bb) * 256)) * 2304 + tokb + tq;
    for (int i = 0; i < 8; i++) {
        int c = c_row + 32 * i;          // c>>5 == i
        uint2 v = *(const uint2*)&T[c][tq + 4 * i];
        *(uint2*)(Yt + obase + (size_t)c * 2304) = v;
    }
}

// ---------------------------------------------------------------------------
// Bilinear 2x upsample from channel-major Yt[bc][48*48] (spatial contiguous).
// Each thread: one oj-pair -> float2 store.
// ---------------------------------------------------------------------------
__global__ __launch_bounds__(256) void upsample_kernel(
    const ushort* __restrict__ Yt, float* __restrict__ out)
{
    int idx = blockIdx.x * 256 + threadIdx.x;    // 36864 blocks
    int m  = idx % 48;
    int t  = idx / 48;
    int oi = t % 96;
    int bc = t / 96;                 // 0..2047

    float fi = oi * 0.5f - 0.25f;
    int i0 = (int)floorf(fi);
    float wi = fi - (float)i0;
    int i1 = i0 + 1 < 47 ? i0 + 1 : 47;
    i0 = i0 > 0 ? i0 : 0;
    int jm = m - 1 > 0 ? m - 1 : 0;
    int jp = m + 1 < 47 ? m + 1 : 47;

    const ushort* r0 = Yt + (size_t)bc * 2304 + i0 * 48;
    const ushort* r1 = Yt + (size_t)bc * 2304 + i1 * 48;
    float a0 = bf2f(r0[jm]), b0 = bf2f(r0[m]), c0 = bf2f(r0[jp]);
    float a1 = bf2f(r1[jm]), b1 = bf2f(r1[m]), c1 = bf2f(r1[jp]);
    float u = 1.f - wi;
    float ha = u * a0 + wi * a1;
    float hb = u * b0 + wi * b1;
    float hc = u * c0 + wi * c1;
    float2 o;
    o.x = 0.25f * ha + 0.75f * hb;
    o.y = 0.75f * hb + 0.25f * hc;
    *(float2*)(out + (size_t)bc * 9216 + oi * 96 + m * 2) = o;
}

// ---------------------------------------------------------------------------
extern "C" void kernel_launch(void* const* d_in, const int* in_sizes, int n_in,
                              void* d_out, int out_size, void* d_ws, size_t ws_size,
                              hipStream_t stream)
{
    (void)in_sizes; (void)n_in; (void)out_size; (void)ws_size;

    // ---- Buffer plan (stream-order-safe reuse; ~29.4 MB of ws) ----
    ushort* ws  = (ushort*)d_ws;
    ushort* Q1  = ws;                         // [9216,256]
    ushort* Q2  = Q1  + 2359296;              // contiguous with Q1
    ushort* KV1 = Q2  + 2359296;              // K4_1 + V4_1
    ushort* KV2 = KV1 + 4718592;              // K4_2 + V4_2
    ushort* wc  = KV2 + 4718592;              // canonical params
    int*    dflag = (int*)(wc + 525824);

    ushort* cqkv1w = wc;                      // [768,256] = q1w ++ kv1w
    ushort* cqkv2w = wc + 196608;             // [768,256] = q2w ++ kv2w
    ushort* cp1w  = wc + 393216;
    ushort* cp2w  = wc + 458752;
    ushort* cp1b  = wc + 524288;
    ushort* cp2b  = wc + 524544;
    ushort* cg1   = wc + 524800;
    ushort* cb1   = wc + 525056;
    ushort* cg2   = wc + 525312;
    ushort* cb2   = wc + 525568;

    float*  outf = (float*)d_out;
    ushort* O1  = (ushort*)d_out;             // bf16 staging (dead pre-upsample)
    ushort* O2  = O1 + 2359296;               // contiguous with O1
    ushort* Xb1 = O2 + 2359296;               // bf16 x1 (dead after QKV gemm)
    ushort* Xb2 = Xb1 + 2359296;              // contiguous with Xb1
    ushort* Z1  = KV2;                        // KV2 dead after attn (launch order)
    ushort* Yt  = Q1;                         // Q1+Q2 dead after attn: 9.4 MB
    (void)Q2; (void)O2; (void)Xb2;

    dim3 blk(256);
    sniff_kernel<<<dim3(1), dim3(64), 0, stream>>>((const ushort*)d_in[0], dflag);
    convert_params<<<dim3(2054), blk, 0, stream>>>(
        d_in[2], d_in[3], d_in[4], d_in[5], d_in[8], d_in[10],
        d_in[9], d_in[11], d_in[12], d_in[13], d_in[14], d_in[15],
        wc, dflag);
    convert_x<<<dim3(2304), blk, 0, stream>>>(d_in[0], d_in[1], Xb1, Xb2, dflag);

    // Merged Q+KV projections for BOTH inputs (M=18432, N=768):
    // Q scaled by scale*log2e, K4/V4 tiled layouts.
    gemm_bt<<<dim3(288, 12), blk, 0, stream>>>(Xb1, cqkv1w, Q1, nullptr,
        18432, 768, 256, 0, dflag, 0, 1, KV1, KV1 + 2359296,
        cqkv2w, nullptr, KV2, KV2 + 2359296, 9216);

    // Both cross attentions in one dispatch. Grid (stream, qb): stream =
    // side*32+bh on blockIdx.x so each stream's 36 blocks share an XCD.
    // 4 waves/block, split-K (18 tiles per wave), LDS combine.
    attn_kernel<<<dim3(64, 36), dim3(256), 0, stream>>>(
        Q1, KV2, KV2 + 2359296, O1,
        Q2, KV1, KV1 + 2359296, O2);

    // Merged output projection + bias + ReLU (M=18432).
    gemm_bt<<<dim3(288, 4), blk, 0, stream>>>(O1, cp1w, Z1, cp1b,
        18432, 256, 256, 1, dflag, 0, 0, nullptr, nullptr,
        cp2w, cp2b, nullptr, nullptr, 9216);

    // LayerNorm + transpose to channel-major (18432 tokens, 32/block).
    lnt_kernel<<<dim3(576), blk, 0, stream>>>(Z1, cg1, cb1, cg2, cb2, Yt);

    // Bilinear 2x upsample into d_out (float32, both outputs, float2/thread).
    upsample_kernel<<<dim3(36864), blk, 0, stream>>>(Yt, outf);
}